// Round 1
// baseline (2223.934 us; speedup 1.0000x reference)
//
#include <hip/hip_runtime.h>
#include <math.h>

#define NB 8
#define N0 8192
#define N1 1024
#define N2 512
#define N3C 256
#define CFEAT 256
#define KNN 16

// IEEE, left-to-right, no fma contraction (matches numpy sum((a-b)**2,-1))
static __device__ __forceinline__ float sq3(float dx, float dy, float dz) {
  return __fadd_rn(__fadd_rn(__fmul_rn(dx, dx), __fmul_rn(dy, dy)), __fmul_rn(dz, dz));
}

// ---------------- 1. per-point feature L2 normalize: [B,C,N] -> [B,C,N] ----------------
__global__ void norm_feats_kernel(const float* __restrict__ f, float* __restrict__ out) {
  int bn = blockIdx.x;               // b*N3C + n
  int b = bn / N3C, n = bn % N3C;
  int c = threadIdx.x;               // 256 threads == CFEAT
  float v = f[((size_t)b * CFEAT + c) * N3C + n];
  float s = v * v;
  for (int off = 32; off; off >>= 1) s += __shfl_xor(s, off, 64);
  __shared__ float wsum[4];
  int wid = threadIdx.x >> 6;
  if ((threadIdx.x & 63) == 0) wsum[wid] = s;
  __syncthreads();
  float tot = wsum[0] + wsum[1] + wsum[2] + wsum[3];
  float r = 1.0f / sqrtf(tot + 1e-8f);
  out[((size_t)b * CFEAT + c) * N3C + n] = v * r;
}

// ---------------- 2. correlation + flow0: writes flow0 [B,3,N3] ----------------
__global__ void corr_flow_kernel(const float* __restrict__ f1n, const float* __restrict__ f2n,
                                 const float* __restrict__ p1, const float* __restrict__ p2,
                                 const float* __restrict__ eps_in, float* __restrict__ flow0) {
  int bn = blockIdx.x;
  int b = bn / N3C, n = bn % N3C;
  int m = threadIdx.x;               // 256 threads == N3C
  __shared__ float f1c[CFEAT];
  __shared__ float p1s[3];
  f1c[m] = f1n[((size_t)b * CFEAT + m) * N3C + n];
  if (m < 3) p1s[m] = p1[((size_t)b * 3 + m) * N3C + n];
  __syncthreads();
  float eps = expf(eps_in[0]) + 0.03f;
  const float* f2b = f2n + (size_t)b * CFEAT * N3C;
  float dot = 0.f;
  for (int c = 0; c < CFEAT; c++) dot += f1c[c] * f2b[(size_t)c * N3C + m];
  float Cv = 1.0f - dot;
  float p2x = p2[((size_t)b * 3 + 0) * N3C + m];
  float p2y = p2[((size_t)b * 3 + 1) * N3C + m];
  float p2z = p2[((size_t)b * 3 + 2) * N3C + m];
  float n1v = p1s[0] * p1s[0] + p1s[1] * p1s[1] + p1s[2] * p1s[2];
  float n2v = p2x * p2x + p2y * p2y + p2z * p2z;
  float dd = n1v + n2v - 2.0f * (p1s[0] * p2x + p1s[1] * p2y + p1s[2] * p2z);
  float corr = (dd < 100.0f) ? expf(-Cv / eps) : 0.0f;
  float s0 = corr, s1 = corr * p2x, s2 = corr * p2y, s3 = corr * p2z;
  for (int off = 32; off; off >>= 1) {
    s0 += __shfl_xor(s0, off, 64); s1 += __shfl_xor(s1, off, 64);
    s2 += __shfl_xor(s2, off, 64); s3 += __shfl_xor(s3, off, 64);
  }
  __shared__ float red[4][4];
  int wid = threadIdx.x >> 6;
  if ((threadIdx.x & 63) == 0) { red[wid][0] = s0; red[wid][1] = s1; red[wid][2] = s2; red[wid][3] = s3; }
  __syncthreads();
  if (threadIdx.x == 0) {
    float r0 = red[0][0] + red[1][0] + red[2][0] + red[3][0];
    float r1 = red[0][1] + red[1][1] + red[2][1] + red[3][1];
    float r2 = red[0][2] + red[1][2] + red[2][2] + red[3][2];
    float r3 = red[0][3] + red[1][3] + red[2][3] + red[3][3];
    float inv = 1.0f / (r0 + 1e-8f);
    flow0[((size_t)b * 3 + 0) * N3C + n] = r1 * inv - p1s[0];
    flow0[((size_t)b * 3 + 1) * N3C + n] = r2 * inv - p1s[1];
    flow0[((size_t)b * 3 + 2) * N3C + n] = r3 * inv - p1s[2];
  }
}

// ---------------- 3. 3-NN inverse-distance interpolation ----------------
// xyz1 [B,3,N], xyz2 [B,3,S], feat [B,C,S] -> out [B,C,N]
__global__ void fprop_kernel(const float* __restrict__ xyz1, const float* __restrict__ xyz2,
                             const float* __restrict__ feat, float* __restrict__ out,
                             int N, int S, int C) {
  __shared__ float sm[4 * 1024];   // x2[3][S] + n2[S], S<=1024
  float* x2s = sm;
  float* n2s = sm + 3 * S;
  int tilesPerB = N / 256;
  int b = blockIdx.x / tilesPerB;
  int n = (blockIdx.x % tilesPerB) * 256 + threadIdx.x;
  for (int i = threadIdx.x; i < S; i += 256) {
    float xx = xyz2[((size_t)b * 3 + 0) * S + i];
    float yy = xyz2[((size_t)b * 3 + 1) * S + i];
    float zz = xyz2[((size_t)b * 3 + 2) * S + i];
    x2s[i] = xx; x2s[S + i] = yy; x2s[2 * S + i] = zz;
    n2s[i] = xx * xx + yy * yy + zz * zz;
  }
  __syncthreads();
  float X = xyz1[((size_t)b * 3 + 0) * N + n];
  float Y = xyz1[((size_t)b * 3 + 1) * N + n];
  float Z = xyz1[((size_t)b * 3 + 2) * N + n];
  float n1v = X * X + Y * Y + Z * Z;
  float d0 = 1e30f, d1 = 1e30f, d2 = 1e30f;
  int i0 = 0, i1 = 0, i2 = 0;
  for (int s = 0; s < S; s++) {
    float d = n1v + n2s[s] - 2.0f * (X * x2s[s] + Y * x2s[S + s] + Z * x2s[2 * S + s]);
    if (d < d0)      { d2 = d1; i2 = i1; d1 = d0; i1 = i0; d0 = d; i0 = s; }
    else if (d < d1) { d2 = d1; i2 = i1; d1 = d; i1 = s; }
    else if (d < d2) { d2 = d; i2 = s; }
  }
  float w0 = 1.0f / (d0 + 1e-8f), w1 = 1.0f / (d1 + 1e-8f), w2 = 1.0f / (d2 + 1e-8f);
  float wsum = w0 + w1 + w2;
  w0 /= wsum; w1 /= wsum; w2 /= wsum;
  for (int c = 0; c < C; c++) {
    const float* fb = feat + ((size_t)b * C + c) * S;
    out[((size_t)b * C + c) * N + n] = w0 * fb[i0] + w1 * fb[i1] + w2 * fb[i2];
  }
}

// ---------------- 4. farthest point sampling (exact scan replica) ----------------
template <int N, int PPL>   // N == 64*PPL, one wave per batch
__global__ void fps_kernel(const float* __restrict__ xyz, int* __restrict__ idx_out) {
  int b = blockIdx.x;
  int lane = threadIdx.x;   // 64 threads
  __shared__ float xs[N], ys[N], zs[N];
  for (int i = lane; i < N; i += 64) {
    xs[i] = xyz[((size_t)b * 3 + 0) * N + i];
    ys[i] = xyz[((size_t)b * 3 + 1) * N + i];
    zs[i] = xyz[((size_t)b * 3 + 2) * N + i];
  }
  __syncthreads();
  float px[PPL], py[PPL], pz[PPL], dist[PPL];
#pragma unroll
  for (int j = 0; j < PPL; j++) {
    int g = lane * PPL + j;
    px[j] = xs[g]; py[j] = ys[g]; pz[j] = zs[g];
    dist[j] = 1e10f;
  }
  int far = 0;
  for (int t = 0; t < N; t++) {
    if (lane == 0) idx_out[(size_t)b * N + t] = far;   // scan outputs carry BEFORE update
    float fx = xs[far], fy = ys[far], fz = zs[far];
    float best = -1.0f; int bi = 0;
#pragma unroll
    for (int j = 0; j < PPL; j++) {
      float d = sq3(px[j] - fx, py[j] - fy, pz[j] - fz);
      float nd = fminf(dist[j], d);
      dist[j] = nd;
      if (nd > best) { best = nd; bi = lane * PPL + j; }   // strict > : first index wins
    }
    for (int off = 1; off < 64; off <<= 1) {
      float ov = __shfl_xor(best, off, 64);
      int oi = __shfl_xor(bi, off, 64);
      if (ov > best || (ov == best && oi < bi)) { best = ov; bi = oi; }
    }
    far = bi;
  }
}

// ---------------- 5. 16-NN per FPS center (set only; order ascending d) ----------------
template <int S, int PPL>   // S == 64*PPL ; one wave per sampled point
__global__ void knn_kernel(const float* __restrict__ xyz, const int* __restrict__ fps_idx,
                           int* __restrict__ knn_out) {
  int gw = blockIdx.x * 4 + (threadIdx.x >> 6);
  int lane = threadIdx.x & 63;
  int b = gw / S, s = gw % S;
  int center = fps_idx[(size_t)b * S + s];
  const float* xb = xyz + (size_t)b * 3 * S;
  float cx = xb[center], cy = xb[S + center], cz = xb[2 * S + center];
  float cn = cx * cx + cy * cy + cz * cz;
  float d[PPL];
#pragma unroll
  for (int j = 0; j < PPL; j++) {
    int g = lane * PPL + j;
    float x = xb[g], y = xb[S + g], z = xb[2 * S + g];
    float pn = x * x + y * y + z * z;
    d[j] = cn + pn - 2.0f * (cx * x + cy * y + cz * z);
  }
  for (int r = 0; r < KNN; r++) {
    float best = 1e30f; int bi = 0;
#pragma unroll
    for (int j = 0; j < PPL; j++)
      if (d[j] < best) { best = d[j]; bi = lane * PPL + j; }
    for (int off = 1; off < 64; off <<= 1) {
      float ov = __shfl_xor(best, off, 64);
      int oi = __shfl_xor(bi, off, 64);
      if (ov < best || (ov == best && oi < bi)) { best = ov; bi = oi; }
    }
    if (lane == 0) knn_out[((size_t)b * S + s) * KNN + r] = bi;
#pragma unroll
    for (int j = 0; j < PPL; j++)
      if (lane * PPL + j == bi) d[j] = 1e30f;
  }
}

// ---------------- 6. grouping: concat(rel_xyz, gathered feats) -> [B, 3+Cin, S*K] ----------------
__global__ void group_kernel(const float* __restrict__ xyz, const float* __restrict__ pts,
                             const int* __restrict__ fps_idx, const int* __restrict__ knn,
                             float* __restrict__ xout, int S, int Cin) {
  int SK = S * KNN;
  int t = blockIdx.x * 256 + threadIdx.x;
  if (t >= NB * SK) return;
  int b = t / SK, sk = t % SK, s = sk / KNN;
  int nb = knn[(size_t)b * SK + sk];
  int ctr = fps_idx[(size_t)b * S + s];
  const float* xb = xyz + (size_t)b * 3 * S;
  int C0 = 3 + Cin;
  float* ob = xout + (size_t)b * C0 * SK;
  ob[0 * SK + sk] = xb[nb] - xb[ctr];
  ob[1 * SK + sk] = xb[S + nb] - xb[S + ctr];
  ob[2 * SK + sk] = xb[2 * S + nb] - xb[2 * S + ctr];
  const float* pb = pts + (size_t)b * Cin * S;
  for (int c = 0; c < Cin; c++) ob[(size_t)(3 + c) * SK + sk] = pb[(size_t)c * S + nb];
}

// ---------------- 7. 1x1 conv (matmul over channels): y[b,d,sk] = sum_c x[b,c,sk]*w[c,d] ----------------
__global__ void mm_kernel(const float* __restrict__ x, const float* __restrict__ w,
                          float* __restrict__ y, int SK, int Cin, int D) {
  int tilesPerB = SK / 256;
  int b = blockIdx.x / tilesPerB;
  int sk = (blockIdx.x % tilesPerB) * 256 + threadIdx.x;
  const float* xb = x + (size_t)b * Cin * SK + sk;
  float* yb = y + (size_t)b * D * SK + sk;
  for (int d0 = 0; d0 < D; d0 += 16) {
    float acc[16];
#pragma unroll
    for (int i = 0; i < 16; i++) acc[i] = 0.f;
    for (int c = 0; c < Cin; c++) {
      float xv = xb[(size_t)c * SK];
      const float* wr = w + (size_t)c * D + d0;   // uniform across lanes -> scalar loads
#pragma unroll
      for (int i = 0; i < 16; i++) acc[i] += xv * wr[i];
    }
#pragma unroll
    for (int i = 0; i < 16; i++) yb[(size_t)(d0 + i) * SK] = acc[i];
  }
}

// ---------------- 8. instance-norm stats per (b,d) over SK contiguous ----------------
__global__ void stats_kernel(const float* __restrict__ y, float* __restrict__ mean,
                             float* __restrict__ rstd, int SK) {
  int bd = blockIdx.x;
  const float* p = y + (size_t)bd * SK;
  float s = 0.f, sq = 0.f;
  for (int i = threadIdx.x; i < SK; i += 256) { float v = p[i]; s += v; sq += v * v; }
  for (int off = 32; off; off >>= 1) { s += __shfl_xor(s, off, 64); sq += __shfl_xor(sq, off, 64); }
  __shared__ float sa[4], sb[4];
  int wid = threadIdx.x >> 6;
  if ((threadIdx.x & 63) == 0) { sa[wid] = s; sb[wid] = sq; }
  __syncthreads();
  if (threadIdx.x == 0) {
    float S1 = sa[0] + sa[1] + sa[2] + sa[3];
    float S2 = sb[0] + sb[1] + sb[2] + sb[3];
    float mu = S1 / (float)SK;
    float var = S2 / (float)SK - mu * mu;
    mean[bd] = mu;
    rstd[bd] = 1.0f / sqrtf(var + 1e-5f);
  }
}

// ---------------- 9. normalize + affine + relu, in place ----------------
__global__ void norm_relu_kernel(float* __restrict__ y, const float* __restrict__ mean,
                                 const float* __restrict__ rstd, const float* __restrict__ g,
                                 const float* __restrict__ beta, int SK, int D) {
  size_t i = (size_t)blockIdx.x * 256 + threadIdx.x;
  if (i >= (size_t)NB * D * SK) return;
  int bd = (int)(i / SK);
  int d = bd % D;
  float v = (y[i] - mean[bd]) * rstd[bd] * g[d] + beta[d];
  y[i] = fmaxf(v, 0.0f);
}

// ---------------- 10. max over K -> [B,D,S] ----------------
__global__ void maxpool_kernel(const float* __restrict__ y, float* __restrict__ out, int S, int D) {
  int t = blockIdx.x * 256 + threadIdx.x;
  if (t >= NB * D * S) return;
  const float* p = y + (size_t)t * KNN;
  float m = p[0];
  for (int k = 1; k < KNN; k++) m = fmaxf(m, p[k]);
  out[t] = m;
}

extern "C" void kernel_launch(void* const* d_in, const int* in_sizes, int n_in,
                              void* d_out, int out_size, void* d_ws, size_t ws_size,
                              hipStream_t stream) {
  const float* pc1_l0 = (const float*)d_in[0];
  const float* pc1_l1 = (const float*)d_in[1];
  const float* pc1_l2 = (const float*)d_in[2];
  const float* pc1_l3 = (const float*)d_in[3];
  const float* pc2_l3 = (const float*)d_in[4];
  const float* feats1 = (const float*)d_in[5];
  const float* feats2 = (const float*)d_in[6];
  const float* epsilon = (const float*)d_in[7];
  const float* sa1_w[3] = {(const float*)d_in[8], (const float*)d_in[9], (const float*)d_in[10]};
  const float* sa1_g[3] = {(const float*)d_in[11], (const float*)d_in[13], (const float*)d_in[15]};
  const float* sa1_b[3] = {(const float*)d_in[12], (const float*)d_in[14], (const float*)d_in[16]};
  const float* sa2_w[3] = {(const float*)d_in[17], (const float*)d_in[18], (const float*)d_in[19]};
  const float* sa2_g[3] = {(const float*)d_in[20], (const float*)d_in[22], (const float*)d_in[24]};
  const float* sa2_b[3] = {(const float*)d_in[21], (const float*)d_in[23], (const float*)d_in[25]};

  char* ws = (char*)d_ws;
  size_t off = 0;
  auto alloc = [&](size_t bytes) { char* p = ws + off; off += (bytes + 255) & ~(size_t)255; return p; };
  // big overlay slots
  float* bufA = (float*)alloc((size_t)NB * 67 * N1 * KNN * 4);  // 35.1MB: x0 slots; y2 overlays A(+B)
  float* bufB = (float*)alloc((size_t)NB * 64 * N1 * KNN * 4);  // 33.5MB: y0
  float* bufC = (float*)alloc((size_t)NB * 64 * N1 * KNN * 4);  // 33.5MB: y1
  float* y2   = bufA;                                            // overlay (x0,y0 dead by then)
  // smalls
  float* f1n      = (float*)alloc((size_t)NB * CFEAT * N3C * 4);
  float* f2n      = (float*)alloc((size_t)NB * CFEAT * N3C * 4);
  float* flow0    = (float*)alloc((size_t)NB * 3 * N3C * 4);
  float* flow0_us = (float*)alloc((size_t)NB * 3 * N2 * 4);
  int*   fps1     = (int*)alloc((size_t)NB * N2 * 4);
  int*   knn1     = (int*)alloc((size_t)NB * N2 * KNN * 4);
  float* cf2      = (float*)alloc((size_t)NB * 64 * N2 * 4);
  float* cf1a     = (float*)alloc((size_t)NB * 64 * N1 * 4);
  int*   fps2     = (int*)alloc((size_t)NB * N1 * 4);
  int*   knn2     = (int*)alloc((size_t)NB * N1 * KNN * 4);
  float* cf1b     = (float*)alloc((size_t)NB * 128 * N1 * 4);
  float* meanb    = (float*)alloc((size_t)NB * 128 * 4);
  float* rstdb    = (float*)alloc((size_t)NB * 128 * 4);
  (void)ws_size; (void)in_sizes; (void)n_in; (void)out_size;

  // ---- stage A: correlation flow at l3 ----
  norm_feats_kernel<<<NB * N3C, 256, 0, stream>>>(feats1, f1n);
  norm_feats_kernel<<<NB * N3C, 256, 0, stream>>>(feats2, f2n);
  corr_flow_kernel<<<NB * N3C, 256, 0, stream>>>(f1n, f2n, pc1_l3, pc2_l3, epsilon, flow0);

  // ---- stage B: upsample flow 256 -> 512 ----
  fprop_kernel<<<NB * (N2 / 256), 256, 0, stream>>>(pc1_l2, pc1_l3, flow0, flow0_us, N2, N3C, 3);

  // ---- helper for SA MLP layer ----
  auto sa_layer = [&](const float* x, const float* w, const float* g, const float* bet,
                      float* y, int SK, int Cin, int D) {
    mm_kernel<<<NB * (SK / 256), 256, 0, stream>>>(x, w, y, SK, Cin, D);
    stats_kernel<<<NB * D, 256, 0, stream>>>(y, meanb, rstdb, SK);
    int total = NB * D * SK;
    norm_relu_kernel<<<(total + 255) / 256, 256, 0, stream>>>(y, meanb, rstdb, g, bet, SK, D);
  };

  // ---- stage C: set abstraction 1 (512 pts, Cin=3) ----
  {
    const int S = N2, SK = S * KNN;
    fps_kernel<N2, N2 / 64><<<NB, 64, 0, stream>>>(pc1_l2, fps1);
    knn_kernel<N2, N2 / 64><<<NB * S / 4, 256, 0, stream>>>(pc1_l2, fps1, knn1);
    group_kernel<<<(NB * SK + 255) / 256, 256, 0, stream>>>(pc1_l2, flow0_us, fps1, knn1, bufA, S, 3);
    sa_layer(bufA, sa1_w[0], sa1_g[0], sa1_b[0], bufB, SK, 6, 32);
    sa_layer(bufB, sa1_w[1], sa1_g[1], sa1_b[1], bufC, SK, 32, 32);
    sa_layer(bufC, sa1_w[2], sa1_g[2], sa1_b[2], y2, SK, 32, 64);
    maxpool_kernel<<<(NB * 64 * S + 255) / 256, 256, 0, stream>>>(y2, cf2, S, 64);
  }

  // ---- stage D: propagate cf2 512 -> 1024 ----
  fprop_kernel<<<NB * (N1 / 256), 256, 0, stream>>>(pc1_l1, pc1_l2, cf2, cf1a, N1, N2, 64);

  // ---- stage E: set abstraction 2 (1024 pts, Cin=64) ----
  {
    const int S = N1, SK = S * KNN;
    fps_kernel<N1, N1 / 64><<<NB, 64, 0, stream>>>(pc1_l1, fps2);
    knn_kernel<N1, N1 / 64><<<NB * S / 4, 256, 0, stream>>>(pc1_l1, fps2, knn2);
    group_kernel<<<(NB * SK + 255) / 256, 256, 0, stream>>>(pc1_l1, cf1a, fps2, knn2, bufA, S, 64);
    sa_layer(bufA, sa2_w[0], sa2_g[0], sa2_b[0], bufB, SK, 67, 64);
    sa_layer(bufB, sa2_w[1], sa2_g[1], sa2_b[1], bufC, SK, 64, 64);
    sa_layer(bufC, sa2_w[2], sa2_g[2], sa2_b[2], y2, SK, 64, 128);
    maxpool_kernel<<<(NB * 128 * S + 255) / 256, 256, 0, stream>>>(y2, cf1b, S, 128);
  }

  // ---- stage F: final propagate 1024 -> 8192 into d_out ----
  fprop_kernel<<<NB * (N0 / 256), 256, 0, stream>>>(pc1_l0, pc1_l1, cf1b, (float*)d_out, N0, N1, 128);
}

// Round 2
// 1363.430 us; speedup vs baseline: 1.6311x; 1.6311x over previous
//
#include <hip/hip_runtime.h>
#include <math.h>

#define NB 8
#define N0 8192
#define N1 1024
#define N2 512
#define N3C 256
#define CFEAT 256
#define KNN 16

// IEEE, left-to-right, no fma contraction (matches numpy sum((a-b)**2,-1))
static __device__ __forceinline__ float sq3(float dx, float dy, float dz) {
  return __fadd_rn(__fadd_rn(__fmul_rn(dx, dx), __fmul_rn(dy, dy)), __fmul_rn(dz, dz));
}

// ---------- DPP wave64 (key,idx) pair reduction: result valid in lane 63 ----------
// MAXSEL=true -> max(key64); false -> min(key64). key64 = (hi<<32)|lo.
template <int CTRL, int RM, bool MAXSEL>
static __device__ __forceinline__ void dpp_step(uint32_t& hi, uint32_t& lo) {
  uint32_t chi = (uint32_t)__builtin_amdgcn_update_dpp((int)hi, (int)hi, CTRL, RM, 0xF, false);
  uint32_t clo = (uint32_t)__builtin_amdgcn_update_dpp((int)lo, (int)lo, CTRL, RM, 0xF, false);
  unsigned long long cand = ((unsigned long long)chi << 32) | clo;
  unsigned long long cur  = ((unsigned long long)hi  << 32) | lo;
  bool take = MAXSEL ? (cand > cur) : (cand < cur);
  if (take) { hi = chi; lo = clo; }
}

template <bool MAXSEL>
static __device__ __forceinline__ void wave_reduce_pair(uint32_t& hi, uint32_t& lo) {
  dpp_step<0x111, 0xF, MAXSEL>(hi, lo);  // row_shr:1
  dpp_step<0x112, 0xF, MAXSEL>(hi, lo);  // row_shr:2
  dpp_step<0x114, 0xF, MAXSEL>(hi, lo);  // row_shr:4
  dpp_step<0x118, 0xF, MAXSEL>(hi, lo);  // row_shr:8  -> lane15/31/47/63 hold row maxes
  dpp_step<0x142, 0xA, MAXSEL>(hi, lo);  // row_bcast:15 into rows 1,3
  dpp_step<0x143, 0xC, MAXSEL>(hi, lo);  // row_bcast:31 into rows 2,3 -> lane 63 full
}

// ---------------- 1. per-point feature L2 normalize: [B,C,N] -> [B,C,N] ----------------
__global__ void norm_feats_kernel(const float* __restrict__ f, float* __restrict__ out) {
  int bn = blockIdx.x;               // b*N3C + n
  int b = bn / N3C, n = bn % N3C;
  int c = threadIdx.x;               // 256 threads == CFEAT
  float v = f[((size_t)b * CFEAT + c) * N3C + n];
  float s = v * v;
  for (int off = 32; off; off >>= 1) s += __shfl_xor(s, off, 64);
  __shared__ float wsum[4];
  int wid = threadIdx.x >> 6;
  if ((threadIdx.x & 63) == 0) wsum[wid] = s;
  __syncthreads();
  float tot = wsum[0] + wsum[1] + wsum[2] + wsum[3];
  float r = 1.0f / sqrtf(tot + 1e-8f);
  out[((size_t)b * CFEAT + c) * N3C + n] = v * r;
}

// ---------------- 2. correlation + flow0: writes flow0 [B,3,N3] ----------------
__global__ void corr_flow_kernel(const float* __restrict__ f1n, const float* __restrict__ f2n,
                                 const float* __restrict__ p1, const float* __restrict__ p2,
                                 const float* __restrict__ eps_in, float* __restrict__ flow0) {
  int bn = blockIdx.x;
  int b = bn / N3C, n = bn % N3C;
  int m = threadIdx.x;               // 256 threads == N3C
  __shared__ float f1c[CFEAT];
  __shared__ float p1s[3];
  f1c[m] = f1n[((size_t)b * CFEAT + m) * N3C + n];
  if (m < 3) p1s[m] = p1[((size_t)b * 3 + m) * N3C + n];
  __syncthreads();
  float eps = expf(eps_in[0]) + 0.03f;
  const float* f2b = f2n + (size_t)b * CFEAT * N3C;
  float dot = 0.f;
  for (int c = 0; c < CFEAT; c++) dot += f1c[c] * f2b[(size_t)c * N3C + m];
  float Cv = 1.0f - dot;
  float p2x = p2[((size_t)b * 3 + 0) * N3C + m];
  float p2y = p2[((size_t)b * 3 + 1) * N3C + m];
  float p2z = p2[((size_t)b * 3 + 2) * N3C + m];
  float n1v = p1s[0] * p1s[0] + p1s[1] * p1s[1] + p1s[2] * p1s[2];
  float n2v = p2x * p2x + p2y * p2y + p2z * p2z;
  float dd = n1v + n2v - 2.0f * (p1s[0] * p2x + p1s[1] * p2y + p1s[2] * p2z);
  float corr = (dd < 100.0f) ? expf(-Cv / eps) : 0.0f;
  float s0 = corr, s1 = corr * p2x, s2 = corr * p2y, s3 = corr * p2z;
  for (int off = 32; off; off >>= 1) {
    s0 += __shfl_xor(s0, off, 64); s1 += __shfl_xor(s1, off, 64);
    s2 += __shfl_xor(s2, off, 64); s3 += __shfl_xor(s3, off, 64);
  }
  __shared__ float red[4][4];
  int wid = threadIdx.x >> 6;
  if ((threadIdx.x & 63) == 0) { red[wid][0] = s0; red[wid][1] = s1; red[wid][2] = s2; red[wid][3] = s3; }
  __syncthreads();
  if (threadIdx.x == 0) {
    float r0 = red[0][0] + red[1][0] + red[2][0] + red[3][0];
    float r1 = red[0][1] + red[1][1] + red[2][1] + red[3][1];
    float r2 = red[0][2] + red[1][2] + red[2][2] + red[3][2];
    float r3 = red[0][3] + red[1][3] + red[2][3] + red[3][3];
    float inv = 1.0f / (r0 + 1e-8f);
    flow0[((size_t)b * 3 + 0) * N3C + n] = r1 * inv - p1s[0];
    flow0[((size_t)b * 3 + 1) * N3C + n] = r2 * inv - p1s[1];
    flow0[((size_t)b * 3 + 2) * N3C + n] = r3 * inv - p1s[2];
  }
}

// ---------------- 3. 3-NN inverse-distance interpolation ----------------
__global__ void fprop_kernel(const float* __restrict__ xyz1, const float* __restrict__ xyz2,
                             const float* __restrict__ feat, float* __restrict__ out,
                             int N, int S, int C) {
  __shared__ float sm[4 * 1024];   // x2[3][S] + n2[S], S<=1024
  float* x2s = sm;
  float* n2s = sm + 3 * S;
  int tilesPerB = N / 256;
  int b = blockIdx.x / tilesPerB;
  int n = (blockIdx.x % tilesPerB) * 256 + threadIdx.x;
  for (int i = threadIdx.x; i < S; i += 256) {
    float xx = xyz2[((size_t)b * 3 + 0) * S + i];
    float yy = xyz2[((size_t)b * 3 + 1) * S + i];
    float zz = xyz2[((size_t)b * 3 + 2) * S + i];
    x2s[i] = xx; x2s[S + i] = yy; x2s[2 * S + i] = zz;
    n2s[i] = xx * xx + yy * yy + zz * zz;
  }
  __syncthreads();
  float X = xyz1[((size_t)b * 3 + 0) * N + n];
  float Y = xyz1[((size_t)b * 3 + 1) * N + n];
  float Z = xyz1[((size_t)b * 3 + 2) * N + n];
  float n1v = X * X + Y * Y + Z * Z;
  float d0 = 1e30f, d1 = 1e30f, d2 = 1e30f;
  int i0 = 0, i1 = 0, i2 = 0;
  for (int s = 0; s < S; s++) {
    float d = n1v + n2s[s] - 2.0f * (X * x2s[s] + Y * x2s[S + s] + Z * x2s[2 * S + s]);
    if (d < d0)      { d2 = d1; i2 = i1; d1 = d0; i1 = i0; d0 = d; i0 = s; }
    else if (d < d1) { d2 = d1; i2 = i1; d1 = d; i1 = s; }
    else if (d < d2) { d2 = d; i2 = s; }
  }
  float w0 = 1.0f / (d0 + 1e-8f), w1 = 1.0f / (d1 + 1e-8f), w2 = 1.0f / (d2 + 1e-8f);
  float wsum = w0 + w1 + w2;
  w0 /= wsum; w1 /= wsum; w2 /= wsum;
  for (int c = 0; c < C; c++) {
    const float* fb = feat + ((size_t)b * C + c) * S;
    out[((size_t)b * C + c) * N + n] = w0 * fb[i0] + w1 * fb[i1] + w2 * fb[i2];
  }
}

// ---------------- 4. farthest point sampling (DPP argmax, exact scan replica) ----------------
template <int N, int PPL>   // N == 64*PPL
static __device__ __forceinline__ void fps_impl(const float* __restrict__ xyz,
                                                int* __restrict__ idx_out, int b, float4* sm) {
  int lane = threadIdx.x;   // 64 threads
  for (int i = lane; i < N; i += 64) {
    float4 v;
    v.x = xyz[((size_t)b * 3 + 0) * N + i];
    v.y = xyz[((size_t)b * 3 + 1) * N + i];
    v.z = xyz[((size_t)b * 3 + 2) * N + i];
    v.w = 0.f;
    sm[i] = v;
  }
  __syncthreads();
  float px[PPL], py[PPL], pz[PPL], dist[PPL];
#pragma unroll
  for (int j = 0; j < PPL; j++) {
    float4 v = sm[lane * PPL + j];
    px[j] = v.x; py[j] = v.y; pz[j] = v.z;
    dist[j] = 1e10f;
  }
  int far = 0;
  idx_out += (size_t)b * N;
  for (int t = 0; t < N; t++) {
    if (lane == 0) idx_out[t] = far;   // scan outputs carry BEFORE update
    float4 f = sm[far];
    float best = -1.0f; int bg = 0;
#pragma unroll
    for (int j = 0; j < PPL; j++) {
      float d = sq3(px[j] - f.x, py[j] - f.y, pz[j] - f.z);
      float nd = fminf(dist[j], d);
      dist[j] = nd;
      if (nd > best) { best = nd; bg = lane * PPL + j; }   // strict > : first index wins
    }
    // pack: dist >= 0 so float bits are order-monotonic; ~idx makes ties pick lowest idx
    uint32_t hi = __float_as_uint(best);
    uint32_t lo = ~(uint32_t)bg;
    wave_reduce_pair<true>(hi, lo);
    far = (int)(~(uint32_t)__builtin_amdgcn_readlane((int)lo, 63));
  }
}

__global__ void fps_both_kernel(const float* __restrict__ xyz_l2, const float* __restrict__ xyz_l1,
                                int* __restrict__ fps1, int* __restrict__ fps2) {
  __shared__ float4 sm[1024];
  if (blockIdx.x < NB) fps_impl<N2, N2 / 64>(xyz_l2, fps1, blockIdx.x, sm);
  else                 fps_impl<N1, N1 / 64>(xyz_l1, fps2, blockIdx.x - NB, sm);
}

// ---------------- 5. 16-NN per FPS center (DPP extract-min x16) ----------------
template <int S, int PPL>   // S == 64*PPL ; one wave per sampled point
static __device__ __forceinline__ void knn_impl(const float* __restrict__ xyz,
                                                const int* __restrict__ fps_idx,
                                                int* __restrict__ knn_out, int gw) {
  int lane = threadIdx.x & 63;
  int b = gw / S, s = gw % S;
  int center = fps_idx[(size_t)b * S + s];
  const float* xb = xyz + (size_t)b * 3 * S;
  float cx = xb[center], cy = xb[S + center], cz = xb[2 * S + center];
  float cn = cx * cx + cy * cy + cz * cz;
  uint32_t kb[PPL];
#pragma unroll
  for (int j = 0; j < PPL; j++) {
    int g = lane * PPL + j;
    float x = xb[g], y = xb[S + g], z = xb[2 * S + g];
    float pn = x * x + y * y + z * z;
    float d = cn + pn - 2.0f * (cx * x + cy * y + cz * z);  // can be slightly negative
    uint32_t bts = __float_as_uint(d);
    kb[j] = bts ^ ((uint32_t)((int)bts >> 31) | 0x80000000u);  // monotonic for all floats
  }
  int* ob = knn_out + ((size_t)b * S + s) * KNN;
  for (int r = 0; r < KNN; r++) {
    uint32_t bh = 0xFFFFFFFFu, bl = 0xFFFFFFFFu;   // sentinel > any real key
#pragma unroll
    for (int j = 0; j < PPL; j++) {
      unsigned long long cand = ((unsigned long long)kb[j] << 32) | (uint32_t)(lane * PPL + j);
      unsigned long long cur  = ((unsigned long long)bh << 32) | bl;
      if (cand < cur) { bh = kb[j]; bl = (uint32_t)(lane * PPL + j); }
    }
    wave_reduce_pair<false>(bh, bl);
    uint32_t widx = (uint32_t)__builtin_amdgcn_readlane((int)bl, 63);
    if (lane == 0) ob[r] = (int)widx;
#pragma unroll
    for (int j = 0; j < PPL; j++)
      if ((uint32_t)(lane * PPL + j) == widx) kb[j] = 0xFFFFFFFFu;
  }
}

__global__ void knn_both_kernel(const float* __restrict__ xyz_l2, const int* __restrict__ fps1,
                                int* __restrict__ knn1,
                                const float* __restrict__ xyz_l1, const int* __restrict__ fps2,
                                int* __restrict__ knn2) {
  int gw = blockIdx.x * 4 + (threadIdx.x >> 6);
  if (gw < NB * N2) knn_impl<N2, N2 / 64>(xyz_l2, fps1, knn1, gw);
  else              knn_impl<N1, N1 / 64>(xyz_l1, fps2, knn2, gw - NB * N2);
}

// ---------------- 6. grouping: concat(rel_xyz, gathered feats) -> [B, 3+Cin, S*K] ----------------
__global__ void group_kernel(const float* __restrict__ xyz, const float* __restrict__ pts,
                             const int* __restrict__ fps_idx, const int* __restrict__ knn,
                             float* __restrict__ xout, int S, int Cin) {
  int SK = S * KNN;
  int t = blockIdx.x * 256 + threadIdx.x;
  if (t >= NB * SK) return;
  int b = t / SK, sk = t % SK, s = sk / KNN;
  int nb = knn[(size_t)b * SK + sk];
  int ctr = fps_idx[(size_t)b * S + s];
  const float* xb = xyz + (size_t)b * 3 * S;
  int C0 = 3 + Cin;
  float* ob = xout + (size_t)b * C0 * SK;
  ob[0 * SK + sk] = xb[nb] - xb[ctr];
  ob[1 * SK + sk] = xb[S + nb] - xb[S + ctr];
  ob[2 * SK + sk] = xb[2 * S + nb] - xb[2 * S + ctr];
  const float* pb = pts + (size_t)b * Cin * S;
  for (int c = 0; c < Cin; c++) ob[(size_t)(3 + c) * SK + sk] = pb[(size_t)c * S + nb];
}

// ---------------- 7. 1x1 conv: full-D register accumulator, x read once ----------------
template <int Cin, int D>
__global__ void mm_kernel(const float* __restrict__ x, const float* __restrict__ w,
                          float* __restrict__ y, int SK) {
  int tilesPerB = SK / 256;
  int b = blockIdx.x / tilesPerB;
  int sk = (blockIdx.x % tilesPerB) * 256 + threadIdx.x;
  const float* xb = x + (size_t)b * Cin * SK + sk;
  float* yb = y + (size_t)b * D * SK + sk;
  float acc[D];
#pragma unroll
  for (int i = 0; i < D; i++) acc[i] = 0.f;
  for (int c = 0; c < Cin; c++) {
    float xv = xb[(size_t)c * SK];
    const float* wr = w + (size_t)c * D;   // uniform across lanes -> scalar loads
#pragma unroll
    for (int i = 0; i < D; i++) acc[i] = fmaf(xv, wr[i], acc[i]);
  }
#pragma unroll
  for (int i = 0; i < D; i++) yb[(size_t)i * SK] = acc[i];
}

// ---------------- 8. instance-norm stats per (b,d) over SK contiguous ----------------
__global__ void stats_kernel(const float* __restrict__ y, float* __restrict__ mean,
                             float* __restrict__ rstd, int SK) {
  int bd = blockIdx.x;
  const float* p = y + (size_t)bd * SK;
  float s = 0.f, sq = 0.f;
  for (int i = threadIdx.x; i < SK; i += 256) { float v = p[i]; s += v; sq += v * v; }
  for (int off = 32; off; off >>= 1) { s += __shfl_xor(s, off, 64); sq += __shfl_xor(sq, off, 64); }
  __shared__ float sa[4], sb[4];
  int wid = threadIdx.x >> 6;
  if ((threadIdx.x & 63) == 0) { sa[wid] = s; sb[wid] = sq; }
  __syncthreads();
  if (threadIdx.x == 0) {
    float S1 = sa[0] + sa[1] + sa[2] + sa[3];
    float S2 = sb[0] + sb[1] + sb[2] + sb[3];
    float mu = S1 / (float)SK;
    float var = S2 / (float)SK - mu * mu;
    mean[bd] = mu;
    rstd[bd] = 1.0f / sqrtf(var + 1e-5f);
  }
}

// ---------------- 9. normalize + affine + relu, in place ----------------
__global__ void norm_relu_kernel(float* __restrict__ y, const float* __restrict__ mean,
                                 const float* __restrict__ rstd, const float* __restrict__ g,
                                 const float* __restrict__ beta, int SK, int D) {
  size_t i = (size_t)blockIdx.x * 256 + threadIdx.x;
  if (i >= (size_t)NB * D * SK) return;
  int bd = (int)(i / SK);
  int d = bd % D;
  float v = (y[i] - mean[bd]) * rstd[bd] * g[d] + beta[d];
  y[i] = fmaxf(v, 0.0f);
}

// ---------------- 10. max over K -> [B,D,S] ----------------
__global__ void maxpool_kernel(const float* __restrict__ y, float* __restrict__ out, int S, int D) {
  int t = blockIdx.x * 256 + threadIdx.x;
  if (t >= NB * D * S) return;
  const float* p = y + (size_t)t * KNN;
  float m = p[0];
  for (int k = 1; k < KNN; k++) m = fmaxf(m, p[k]);
  out[t] = m;
}

extern "C" void kernel_launch(void* const* d_in, const int* in_sizes, int n_in,
                              void* d_out, int out_size, void* d_ws, size_t ws_size,
                              hipStream_t stream) {
  const float* pc1_l0 = (const float*)d_in[0];
  const float* pc1_l1 = (const float*)d_in[1];
  const float* pc1_l2 = (const float*)d_in[2];
  const float* pc1_l3 = (const float*)d_in[3];
  const float* pc2_l3 = (const float*)d_in[4];
  const float* feats1 = (const float*)d_in[5];
  const float* feats2 = (const float*)d_in[6];
  const float* epsilon = (const float*)d_in[7];
  const float* sa1_w[3] = {(const float*)d_in[8], (const float*)d_in[9], (const float*)d_in[10]};
  const float* sa1_g[3] = {(const float*)d_in[11], (const float*)d_in[13], (const float*)d_in[15]};
  const float* sa1_b[3] = {(const float*)d_in[12], (const float*)d_in[14], (const float*)d_in[16]};
  const float* sa2_w[3] = {(const float*)d_in[17], (const float*)d_in[18], (const float*)d_in[19]};
  const float* sa2_g[3] = {(const float*)d_in[20], (const float*)d_in[22], (const float*)d_in[24]};
  const float* sa2_b[3] = {(const float*)d_in[21], (const float*)d_in[23], (const float*)d_in[25]};

  char* ws = (char*)d_ws;
  size_t off = 0;
  auto alloc = [&](size_t bytes) { char* p = ws + off; off += (bytes + 255) & ~(size_t)255; return p; };
  // big overlay slots
  float* bufA = (float*)alloc((size_t)NB * 67 * N1 * KNN * 4);  // x0 slots; y2 overlays A
  float* bufB = (float*)alloc((size_t)NB * 64 * N1 * KNN * 4);  // y0
  float* bufC = (float*)alloc((size_t)NB * 64 * N1 * KNN * 4);  // y1
  float* y2   = bufA;                                            // overlay (x0,y0 dead by then)
  // smalls
  float* f1n      = (float*)alloc((size_t)NB * CFEAT * N3C * 4);
  float* f2n      = (float*)alloc((size_t)NB * CFEAT * N3C * 4);
  float* flow0    = (float*)alloc((size_t)NB * 3 * N3C * 4);
  float* flow0_us = (float*)alloc((size_t)NB * 3 * N2 * 4);
  int*   fps1     = (int*)alloc((size_t)NB * N2 * 4);
  int*   knn1     = (int*)alloc((size_t)NB * N2 * KNN * 4);
  float* cf2      = (float*)alloc((size_t)NB * 64 * N2 * 4);
  float* cf1a     = (float*)alloc((size_t)NB * 64 * N1 * 4);
  int*   fps2     = (int*)alloc((size_t)NB * N1 * 4);
  int*   knn2     = (int*)alloc((size_t)NB * N1 * KNN * 4);
  float* cf1b     = (float*)alloc((size_t)NB * 128 * N1 * 4);
  float* meanb    = (float*)alloc((size_t)NB * 128 * 4);
  float* rstdb    = (float*)alloc((size_t)NB * 128 * 4);
  (void)ws_size; (void)in_sizes; (void)n_in; (void)out_size;

  // ---- independent-of-everything: both FPS (merged), then both kNN (merged) ----
  fps_both_kernel<<<2 * NB, 64, 0, stream>>>(pc1_l2, pc1_l1, fps1, fps2);
  knn_both_kernel<<<(NB * N2 + NB * N1) / 4, 256, 0, stream>>>(pc1_l2, fps1, knn1,
                                                               pc1_l1, fps2, knn2);

  // ---- stage A: correlation flow at l3 ----
  norm_feats_kernel<<<NB * N3C, 256, 0, stream>>>(feats1, f1n);
  norm_feats_kernel<<<NB * N3C, 256, 0, stream>>>(feats2, f2n);
  corr_flow_kernel<<<NB * N3C, 256, 0, stream>>>(f1n, f2n, pc1_l3, pc2_l3, epsilon, flow0);

  // ---- stage B: upsample flow 256 -> 512 ----
  fprop_kernel<<<NB * (N2 / 256), 256, 0, stream>>>(pc1_l2, pc1_l3, flow0, flow0_us, N2, N3C, 3);

  auto post = [&](float* y, const float* g, const float* bet, int SK, int D) {
    stats_kernel<<<NB * D, 256, 0, stream>>>(y, meanb, rstdb, SK);
    int total = NB * D * SK;
    norm_relu_kernel<<<(total + 255) / 256, 256, 0, stream>>>(y, meanb, rstdb, g, bet, SK, D);
  };

  // ---- stage C: set abstraction 1 (512 pts, Cin=3) ----
  {
    const int S = N2, SK = S * KNN;
    group_kernel<<<(NB * SK + 255) / 256, 256, 0, stream>>>(pc1_l2, flow0_us, fps1, knn1, bufA, S, 3);
    mm_kernel<6, 32><<<NB * (SK / 256), 256, 0, stream>>>(bufA, sa1_w[0], bufB, SK);
    post(bufB, sa1_g[0], sa1_b[0], SK, 32);
    mm_kernel<32, 32><<<NB * (SK / 256), 256, 0, stream>>>(bufB, sa1_w[1], bufC, SK);
    post(bufC, sa1_g[1], sa1_b[1], SK, 32);
    mm_kernel<32, 64><<<NB * (SK / 256), 256, 0, stream>>>(bufC, sa1_w[2], y2, SK);
    post(y2, sa1_g[2], sa1_b[2], SK, 64);
    maxpool_kernel<<<(NB * 64 * S + 255) / 256, 256, 0, stream>>>(y2, cf2, S, 64);
  }

  // ---- stage D: propagate cf2 512 -> 1024 ----
  fprop_kernel<<<NB * (N1 / 256), 256, 0, stream>>>(pc1_l1, pc1_l2, cf2, cf1a, N1, N2, 64);

  // ---- stage E: set abstraction 2 (1024 pts, Cin=64) ----
  {
    const int S = N1, SK = S * KNN;
    group_kernel<<<(NB * SK + 255) / 256, 256, 0, stream>>>(pc1_l1, cf1a, fps2, knn2, bufA, S, 64);
    mm_kernel<67, 64><<<NB * (SK / 256), 256, 0, stream>>>(bufA, sa2_w[0], bufB, SK);
    post(bufB, sa2_g[0], sa2_b[0], SK, 64);
    mm_kernel<64, 64><<<NB * (SK / 256), 256, 0, stream>>>(bufB, sa2_w[1], bufC, SK);
    post(bufC, sa2_g[1], sa2_b[1], SK, 64);
    mm_kernel<64, 128><<<NB * (SK / 256), 256, 0, stream>>>(bufC, sa2_w[2], y2, SK);
    post(y2, sa2_g[2], sa2_b[2], SK, 128);
    maxpool_kernel<<<(NB * 128 * S + 255) / 256, 256, 0, stream>>>(y2, cf1b, S, 128);
  }

  // ---- stage F: final propagate 1024 -> 8192 into d_out ----
  fprop_kernel<<<NB * (N0 / 256), 256, 0, stream>>>(pc1_l0, pc1_l1, cf1b, (float*)d_out, N0, N1, 128);
}

// Round 3
// 1237.116 us; speedup vs baseline: 1.7977x; 1.1021x over previous
//
#include <hip/hip_runtime.h>
#include <math.h>

#define NB 8
#define N0 8192
#define N1 1024
#define N2 512
#define N3C 256
#define CFEAT 256
#define KNN 16

typedef float v2f __attribute__((ext_vector_type(2)));

// VOP3P packed f32 ops (CDNA2+). Per-component IEEE rn — identical rounding to
// scalar __fadd_rn/__fmul_rn, 2 lanes' worth per instruction.
static __device__ __forceinline__ v2f pk_add(v2f a, v2f b) {
  v2f r; asm("v_pk_add_f32 %0, %1, %2" : "=v"(r) : "v"(a), "v"(b)); return r;
}
static __device__ __forceinline__ v2f pk_mul(v2f a, v2f b) {
  v2f r; asm("v_pk_mul_f32 %0, %1, %2" : "=v"(r) : "v"(a), "v"(b)); return r;
}

// ---------- DPP wave64 f32 max step: combine with lane-shifted value ----------
template <int CTRL, int RM>
static __device__ __forceinline__ float dpp_maxstep(float x) {
  int xi = __float_as_int(x);
  int mv = __builtin_amdgcn_update_dpp(xi, xi, CTRL, RM, 0xF, false);
  return fmaxf(x, __int_as_float(mv));
}
static __device__ __forceinline__ float wave_max(float x) {
  x = dpp_maxstep<0x111, 0xF>(x);  // row_shr:1
  x = dpp_maxstep<0x112, 0xF>(x);  // row_shr:2
  x = dpp_maxstep<0x114, 0xF>(x);  // row_shr:4
  x = dpp_maxstep<0x118, 0xF>(x);  // row_shr:8
  x = dpp_maxstep<0x142, 0xA>(x);  // row_bcast:15
  x = dpp_maxstep<0x143, 0xC>(x);  // row_bcast:31 -> lane 63 holds full max
  return __int_as_float(__builtin_amdgcn_readlane(__float_as_int(x), 63));
}

// ---------- DPP wave64 (key,idx) pair reduction for kNN (min) ----------
template <int CTRL, int RM, bool MAXSEL>
static __device__ __forceinline__ void dpp_step(uint32_t& hi, uint32_t& lo) {
  uint32_t chi = (uint32_t)__builtin_amdgcn_update_dpp((int)hi, (int)hi, CTRL, RM, 0xF, false);
  uint32_t clo = (uint32_t)__builtin_amdgcn_update_dpp((int)lo, (int)lo, CTRL, RM, 0xF, false);
  unsigned long long cand = ((unsigned long long)chi << 32) | clo;
  unsigned long long cur  = ((unsigned long long)hi  << 32) | lo;
  bool take = MAXSEL ? (cand > cur) : (cand < cur);
  if (take) { hi = chi; lo = clo; }
}
template <bool MAXSEL>
static __device__ __forceinline__ void wave_reduce_pair(uint32_t& hi, uint32_t& lo) {
  dpp_step<0x111, 0xF, MAXSEL>(hi, lo);
  dpp_step<0x112, 0xF, MAXSEL>(hi, lo);
  dpp_step<0x114, 0xF, MAXSEL>(hi, lo);
  dpp_step<0x118, 0xF, MAXSEL>(hi, lo);
  dpp_step<0x142, 0xA, MAXSEL>(hi, lo);
  dpp_step<0x143, 0xC, MAXSEL>(hi, lo);
}

// ---------------- 1. per-point feature L2 normalize (both tensors in one grid) ----------------
__global__ void norm_feats2_kernel(const float* __restrict__ fa, const float* __restrict__ fb,
                                   float* __restrict__ oa, float* __restrict__ ob) {
  int bn = blockIdx.x;
  const float* f; float* o;
  if (bn >= NB * N3C) { f = fb; o = ob; bn -= NB * N3C; } else { f = fa; o = oa; }
  int b = bn / N3C, n = bn % N3C;
  int c = threadIdx.x;               // 256 threads == CFEAT
  float v = f[((size_t)b * CFEAT + c) * N3C + n];
  float s = v * v;
  for (int off = 32; off; off >>= 1) s += __shfl_xor(s, off, 64);
  __shared__ float wsum[4];
  int wid = threadIdx.x >> 6;
  if ((threadIdx.x & 63) == 0) wsum[wid] = s;
  __syncthreads();
  float tot = wsum[0] + wsum[1] + wsum[2] + wsum[3];
  float r = 1.0f / sqrtf(tot + 1e-8f);
  o[((size_t)b * CFEAT + c) * N3C + n] = v * r;
}

// ---------------- 2. correlation + flow0 (s-major output [B][N3][3]) ----------------
__global__ void corr_flow_kernel(const float* __restrict__ f1n, const float* __restrict__ f2n,
                                 const float* __restrict__ p1, const float* __restrict__ p2,
                                 const float* __restrict__ eps_in, float* __restrict__ flow0) {
  int bn = blockIdx.x;
  int b = bn / N3C, n = bn % N3C;
  int m = threadIdx.x;               // 256 threads == N3C
  __shared__ float f1c[CFEAT];
  __shared__ float p1s[3];
  f1c[m] = f1n[((size_t)b * CFEAT + m) * N3C + n];
  if (m < 3) p1s[m] = p1[((size_t)b * 3 + m) * N3C + n];
  __syncthreads();
  float eps = expf(eps_in[0]) + 0.03f;
  const float* f2b = f2n + (size_t)b * CFEAT * N3C;
  float dot = 0.f;
  for (int c = 0; c < CFEAT; c++) dot += f1c[c] * f2b[(size_t)c * N3C + m];
  float Cv = 1.0f - dot;
  float p2x = p2[((size_t)b * 3 + 0) * N3C + m];
  float p2y = p2[((size_t)b * 3 + 1) * N3C + m];
  float p2z = p2[((size_t)b * 3 + 2) * N3C + m];
  float n1v = p1s[0] * p1s[0] + p1s[1] * p1s[1] + p1s[2] * p1s[2];
  float n2v = p2x * p2x + p2y * p2y + p2z * p2z;
  float dd = n1v + n2v - 2.0f * (p1s[0] * p2x + p1s[1] * p2y + p1s[2] * p2z);
  float corr = (dd < 100.0f) ? expf(-Cv / eps) : 0.0f;
  float s0 = corr, s1 = corr * p2x, s2 = corr * p2y, s3 = corr * p2z;
  for (int off = 32; off; off >>= 1) {
    s0 += __shfl_xor(s0, off, 64); s1 += __shfl_xor(s1, off, 64);
    s2 += __shfl_xor(s2, off, 64); s3 += __shfl_xor(s3, off, 64);
  }
  __shared__ float red[4][4];
  int wid = threadIdx.x >> 6;
  if ((threadIdx.x & 63) == 0) { red[wid][0] = s0; red[wid][1] = s1; red[wid][2] = s2; red[wid][3] = s3; }
  __syncthreads();
  if (threadIdx.x == 0) {
    float r0 = red[0][0] + red[1][0] + red[2][0] + red[3][0];
    float r1 = red[0][1] + red[1][1] + red[2][1] + red[3][1];
    float r2 = red[0][2] + red[1][2] + red[2][2] + red[3][2];
    float r3 = red[0][3] + red[1][3] + red[2][3] + red[3][3];
    float inv = 1.0f / (r0 + 1e-8f);
    float* fo = flow0 + ((size_t)b * N3C + n) * 3;
    fo[0] = r1 * inv - p1s[0];
    fo[1] = r2 * inv - p1s[1];
    fo[2] = r3 * inv - p1s[2];
  }
}

// ---------------- 3. 3-NN inverse-distance interpolation (featT is [B][S][C]) ----------------
template <int C, bool TOUT>
__global__ void fprop_kernel(const float* __restrict__ xyz1, const float* __restrict__ xyz2,
                             const float* __restrict__ featT, float* __restrict__ out,
                             int N, int S) {
  __shared__ float sm[4 * 1024];   // x2[3][S] + n2[S], S<=1024
  float* x2s = sm;
  float* n2s = sm + 3 * S;
  int tilesPerB = N / 256;
  int b = blockIdx.x / tilesPerB;
  int n = (blockIdx.x % tilesPerB) * 256 + threadIdx.x;
  for (int i = threadIdx.x; i < S; i += 256) {
    float xx = xyz2[((size_t)b * 3 + 0) * S + i];
    float yy = xyz2[((size_t)b * 3 + 1) * S + i];
    float zz = xyz2[((size_t)b * 3 + 2) * S + i];
    x2s[i] = xx; x2s[S + i] = yy; x2s[2 * S + i] = zz;
    n2s[i] = xx * xx + yy * yy + zz * zz;
  }
  __syncthreads();
  float X = xyz1[((size_t)b * 3 + 0) * N + n];
  float Y = xyz1[((size_t)b * 3 + 1) * N + n];
  float Z = xyz1[((size_t)b * 3 + 2) * N + n];
  float n1v = X * X + Y * Y + Z * Z;
  float d0 = 1e30f, d1 = 1e30f, d2 = 1e30f;
  int i0 = 0, i1 = 0, i2 = 0;
  for (int s = 0; s < S; s++) {
    float d = n1v + n2s[s] - 2.0f * (X * x2s[s] + Y * x2s[S + s] + Z * x2s[2 * S + s]);
    if (d < d0)      { d2 = d1; i2 = i1; d1 = d0; i1 = i0; d0 = d; i0 = s; }
    else if (d < d1) { d2 = d1; i2 = i1; d1 = d; i1 = s; }
    else if (d < d2) { d2 = d; i2 = s; }
  }
  float w0 = 1.0f / (d0 + 1e-8f), w1 = 1.0f / (d1 + 1e-8f), w2 = 1.0f / (d2 + 1e-8f);
  float wsum = w0 + w1 + w2;
  w0 /= wsum; w1 /= wsum; w2 /= wsum;
  const float* g0 = featT + ((size_t)b * S + i0) * C;
  const float* g1 = featT + ((size_t)b * S + i1) * C;
  const float* g2 = featT + ((size_t)b * S + i2) * C;
  if constexpr (C % 4 == 0) {
    const float4* v0 = (const float4*)g0;
    const float4* v1 = (const float4*)g1;
    const float4* v2 = (const float4*)g2;
#pragma unroll 4
    for (int c4 = 0; c4 < C / 4; c4++) {
      float4 a = v0[c4], bb = v1[c4], cc = v2[c4];
      float4 r;
      r.x = w0 * a.x + w1 * bb.x + w2 * cc.x;
      r.y = w0 * a.y + w1 * bb.y + w2 * cc.y;
      r.z = w0 * a.z + w1 * bb.z + w2 * cc.z;
      r.w = w0 * a.w + w1 * bb.w + w2 * cc.w;
      if constexpr (TOUT) {
        ((float4*)(out + ((size_t)b * N + n) * C))[c4] = r;
      } else {
        out[((size_t)b * C + 4 * c4 + 0) * N + n] = r.x;
        out[((size_t)b * C + 4 * c4 + 1) * N + n] = r.y;
        out[((size_t)b * C + 4 * c4 + 2) * N + n] = r.z;
        out[((size_t)b * C + 4 * c4 + 3) * N + n] = r.w;
      }
    }
  } else {
#pragma unroll
    for (int c = 0; c < C; c++) {
      float val = w0 * g0[c] + w1 * g1[c] + w2 * g2[c];
      if constexpr (TOUT) out[((size_t)b * N + n) * C + c] = val;
      else                out[((size_t)b * C + c) * N + n] = val;
    }
  }
}

// ---------------- 4. FPS: packed-f32 update + f32 DPP max + ballot argmax ----------------
template <int N, int PPL>   // N == 64*PPL
static __device__ __forceinline__ void fps_impl(const float* __restrict__ xyz,
                                                int* __restrict__ idx_out, int b, float4* sm) {
  int lane = threadIdx.x;   // 64 threads
  for (int i = lane; i < N; i += 64) {
    float4 v;
    v.x = xyz[((size_t)b * 3 + 0) * N + i];
    v.y = xyz[((size_t)b * 3 + 1) * N + i];
    v.z = xyz[((size_t)b * 3 + 2) * N + i];
    v.w = 0.f;
    sm[i] = v;
  }
  __syncthreads();
  v2f px[PPL / 2], py[PPL / 2], pz[PPL / 2];
  float dist[PPL];
#pragma unroll
  for (int k = 0; k < PPL / 2; k++) {
    float4 a = sm[lane * PPL + 2 * k];
    float4 c = sm[lane * PPL + 2 * k + 1];
    px[k] = v2f{a.x, c.x}; py[k] = v2f{a.y, c.y}; pz[k] = v2f{a.z, c.z};
    dist[2 * k] = 1e10f; dist[2 * k + 1] = 1e10f;
  }
  int far = 0;
  idx_out += (size_t)b * N;
  for (int t = 0; t < N; t++) {
    if (lane == 0) idx_out[t] = far;   // scan emits carry BEFORE update
    float4 f = sm[far];
    // x + (-y) == x - y exactly (IEEE); pk ops are per-component rn
    v2f nfx = v2f{-f.x, -f.x}, nfy = v2f{-f.y, -f.y}, nfz = v2f{-f.z, -f.z};
    float best = -1.0f; int bg = 0;
#pragma unroll
    for (int k = 0; k < PPL / 2; k++) {
      v2f dx = pk_add(px[k], nfx);
      v2f dy = pk_add(py[k], nfy);
      v2f dz = pk_add(pz[k], nfz);
      v2f dd = pk_add(pk_add(pk_mul(dx, dx), pk_mul(dy, dy)), pk_mul(dz, dz));
      float n0 = fminf(dist[2 * k], dd.x);
      float n1 = fminf(dist[2 * k + 1], dd.y);
      dist[2 * k] = n0; dist[2 * k + 1] = n1;
      if (n0 > best) { best = n0; bg = lane * PPL + 2 * k; }       // strict >: first idx wins
      if (n1 > best) { best = n1; bg = lane * PPL + 2 * k + 1; }
    }
    float M = wave_max(best);
    // lanes own index-contiguous chunks -> lowest qualifying lane == lowest index
    unsigned long long msk = __ballot(best == M);
    int wl = __ffsll((unsigned long long)msk) - 1;
    far = __builtin_amdgcn_readlane(bg, wl);
  }
}

__global__ void fps_both_kernel(const float* __restrict__ xyz_l2, const float* __restrict__ xyz_l1,
                                int* __restrict__ fps1, int* __restrict__ fps2) {
  __shared__ float4 sm[1024];
  if (blockIdx.x < NB) fps_impl<N2, N2 / 64>(xyz_l2, fps1, blockIdx.x, sm);
  else                 fps_impl<N1, N1 / 64>(xyz_l1, fps2, blockIdx.x - NB, sm);
}

// ---------------- 5. 16-NN per FPS center (DPP extract-min x16) ----------------
template <int S, int PPL>
static __device__ __forceinline__ void knn_impl(const float* __restrict__ xyz,
                                                const int* __restrict__ fps_idx,
                                                int* __restrict__ knn_out, int gw) {
  int lane = threadIdx.x & 63;
  int b = gw / S, s = gw % S;
  int center = fps_idx[(size_t)b * S + s];
  const float* xb = xyz + (size_t)b * 3 * S;
  float cx = xb[center], cy = xb[S + center], cz = xb[2 * S + center];
  float cn = cx * cx + cy * cy + cz * cz;
  uint32_t kb[PPL];
#pragma unroll
  for (int j = 0; j < PPL; j++) {
    int g = lane * PPL + j;
    float x = xb[g], y = xb[S + g], z = xb[2 * S + g];
    float pn = x * x + y * y + z * z;
    float d = cn + pn - 2.0f * (cx * x + cy * y + cz * z);
    uint32_t bts = __float_as_uint(d);
    kb[j] = bts ^ ((uint32_t)((int)bts >> 31) | 0x80000000u);  // order-monotonic for all floats
  }
  int* ob = knn_out + ((size_t)b * S + s) * KNN;
  for (int r = 0; r < KNN; r++) {
    uint32_t bh = 0xFFFFFFFFu, bl = 0xFFFFFFFFu;
#pragma unroll
    for (int j = 0; j < PPL; j++) {
      unsigned long long cand = ((unsigned long long)kb[j] << 32) | (uint32_t)(lane * PPL + j);
      unsigned long long cur  = ((unsigned long long)bh << 32) | bl;
      if (cand < cur) { bh = kb[j]; bl = (uint32_t)(lane * PPL + j); }
    }
    wave_reduce_pair<false>(bh, bl);
    uint32_t widx = (uint32_t)__builtin_amdgcn_readlane((int)bl, 63);
    if (lane == 0) ob[r] = (int)widx;
#pragma unroll
    for (int j = 0; j < PPL; j++)
      if ((uint32_t)(lane * PPL + j) == widx) kb[j] = 0xFFFFFFFFu;
  }
}

__global__ void knn_both_kernel(const float* __restrict__ xyz_l2, const int* __restrict__ fps1,
                                int* __restrict__ knn1,
                                const float* __restrict__ xyz_l1, const int* __restrict__ fps2,
                                int* __restrict__ knn2) {
  int gw = blockIdx.x * 4 + (threadIdx.x >> 6);
  if (gw < NB * N2) knn_impl<N2, N2 / 64>(xyz_l2, fps1, knn1, gw);
  else              knn_impl<N1, N1 / 64>(xyz_l1, fps2, knn2, gw - NB * N2);
}

// ---------------- 6. layer-0 matmul with fused gather (group+mm) ----------------
// in-channels = 3 (rel xyz) + CF (gathered feats, point-major [B][S][CF])
template <int CF, int D>
__global__ void mm0_kernel(const float* __restrict__ xyz, const float* __restrict__ featsT,
                           const int* __restrict__ fps_idx, const int* __restrict__ knn,
                           const float* __restrict__ w, float* __restrict__ y, int S) {
  const int SK = S * KNN;
  int t = blockIdx.x * 256 + threadIdx.x;
  if (t >= NB * SK) return;
  int b = t / SK, sk = t % SK, s = sk / KNN;
  int nb = knn[(size_t)b * SK + sk];
  int ctr = fps_idx[(size_t)b * S + s];
  const float* xb = xyz + (size_t)b * 3 * S;
  float r0 = xb[nb] - xb[ctr];
  float r1 = xb[S + nb] - xb[S + ctr];
  float r2 = xb[2 * S + nb] - xb[2 * S + ctr];
  float acc[D];
#pragma unroll
  for (int i = 0; i < D; i++)
    acc[i] = fmaf(r0, w[i], fmaf(r1, w[D + i], r2 * w[2 * D + i]));
  const float* pb = featsT + ((size_t)b * S + nb) * CF;
  if constexpr (CF % 4 == 0) {
    const float4* pv = (const float4*)pb;
    for (int c4 = 0; c4 < CF / 4; c4++) {
      float4 v = pv[c4];
      const float* wr = w + (size_t)(3 + 4 * c4) * D;
#pragma unroll
      for (int i = 0; i < D; i++)
        acc[i] = fmaf(v.x, wr[i],
                 fmaf(v.y, wr[D + i],
                 fmaf(v.z, wr[2 * D + i],
                 fmaf(v.w, wr[3 * D + i], acc[i]))));
    }
  } else {
#pragma unroll
    for (int c = 0; c < CF; c++) {
      float xv = pb[c];
      const float* wr = w + (size_t)(3 + c) * D;
#pragma unroll
      for (int i = 0; i < D; i++) acc[i] = fmaf(xv, wr[i], acc[i]);
    }
  }
  float* yb = y + (size_t)b * D * SK + sk;
#pragma unroll
  for (int i = 0; i < D; i++) yb[(size_t)i * SK] = acc[i];
}

// ---------------- 7. matmul with fused input-normalize+relu (prev layer's IN) ----------------
template <int Cin, int D>
__global__ void mm_norm_kernel(const float* __restrict__ x, const float* __restrict__ w,
                               const float* __restrict__ mean, const float* __restrict__ rstd,
                               const float* __restrict__ g, const float* __restrict__ beta,
                               float* __restrict__ y, int SK) {
  int tilesPerB = SK / 256;
  int b = blockIdx.x / tilesPerB;
  int sk = (blockIdx.x % tilesPerB) * 256 + threadIdx.x;
  const float* xb = x + (size_t)b * Cin * SK + sk;
  float* yb = y + (size_t)b * D * SK + sk;
  float acc[D];
#pragma unroll
  for (int i = 0; i < D; i++) acc[i] = 0.f;
  for (int c = 0; c < Cin; c++) {
    float mu = mean[b * Cin + c], rs = rstd[b * Cin + c];
    float sc = rs * g[c];
    float sh = fmaf(-mu, sc, beta[c]);
    float xv = fmaxf(fmaf(xb[(size_t)c * SK], sc, sh), 0.f);
    const float* wr = w + (size_t)c * D;
#pragma unroll
    for (int i = 0; i < D; i++) acc[i] = fmaf(xv, wr[i], acc[i]);
  }
#pragma unroll
  for (int i = 0; i < D; i++) yb[(size_t)i * SK] = acc[i];
}

// ---------------- 8. instance-norm stats per (b,d) over SK contiguous ----------------
__global__ void stats_kernel(const float* __restrict__ y, float* __restrict__ mean,
                             float* __restrict__ rstd, int SK) {
  int bd = blockIdx.x;
  const float* p = y + (size_t)bd * SK;
  float s = 0.f, sq = 0.f;
  for (int i = threadIdx.x; i < SK; i += 256) { float v = p[i]; s += v; sq += v * v; }
  for (int off = 32; off; off >>= 1) { s += __shfl_xor(s, off, 64); sq += __shfl_xor(sq, off, 64); }
  __shared__ float sa[4], sb[4];
  int wid = threadIdx.x >> 6;
  if ((threadIdx.x & 63) == 0) { sa[wid] = s; sb[wid] = sq; }
  __syncthreads();
  if (threadIdx.x == 0) {
    float S1 = sa[0] + sa[1] + sa[2] + sa[3];
    float S2 = sb[0] + sb[1] + sb[2] + sb[3];
    float mu = S1 / (float)SK;
    float var = S2 / (float)SK - mu * mu;
    mean[bd] = mu;
    rstd[bd] = 1.0f / sqrtf(var + 1e-5f);
  }
}

// ---------------- 9. fused normalize+relu+max-over-K; writes point-major [B][S][D] ----------------
template <int D>
__global__ void maxpool_norm_kernel(const float* __restrict__ y, const float* __restrict__ mean,
                                    const float* __restrict__ rstd, const float* __restrict__ g,
                                    const float* __restrict__ beta, float* __restrict__ outT, int S) {
  int t = blockIdx.x * 256 + threadIdx.x;      // t = (b*D + d)*S + s
  if (t >= NB * D * S) return;
  int s = t % S;
  int bd = t / S;
  int d = bd % D, b = bd / D;
  float mu = mean[bd], sc = rstd[bd] * g[d];
  float sh = fmaf(-mu, sc, beta[d]);
  const float4* p = (const float4*)(y + (size_t)t * KNN);
  float m = -1e30f;
#pragma unroll
  for (int q = 0; q < 4; q++) {
    float4 v = p[q];
    m = fmaxf(m, fmaf(v.x, sc, sh)); m = fmaxf(m, fmaf(v.y, sc, sh));
    m = fmaxf(m, fmaf(v.z, sc, sh)); m = fmaxf(m, fmaf(v.w, sc, sh));
  }
  outT[((size_t)b * S + s) * D + d] = fmaxf(m, 0.f);   // relu(max) == max(relu)
}

extern "C" void kernel_launch(void* const* d_in, const int* in_sizes, int n_in,
                              void* d_out, int out_size, void* d_ws, size_t ws_size,
                              hipStream_t stream) {
  const float* pc1_l0 = (const float*)d_in[0];
  const float* pc1_l1 = (const float*)d_in[1];
  const float* pc1_l2 = (const float*)d_in[2];
  const float* pc1_l3 = (const float*)d_in[3];
  const float* pc2_l3 = (const float*)d_in[4];
  const float* feats1 = (const float*)d_in[5];
  const float* feats2 = (const float*)d_in[6];
  const float* epsilon = (const float*)d_in[7];
  const float* sa1_w[3] = {(const float*)d_in[8], (const float*)d_in[9], (const float*)d_in[10]};
  const float* sa1_g[3] = {(const float*)d_in[11], (const float*)d_in[13], (const float*)d_in[15]};
  const float* sa1_b[3] = {(const float*)d_in[12], (const float*)d_in[14], (const float*)d_in[16]};
  const float* sa2_w[3] = {(const float*)d_in[17], (const float*)d_in[18], (const float*)d_in[19]};
  const float* sa2_g[3] = {(const float*)d_in[20], (const float*)d_in[22], (const float*)d_in[24]};
  const float* sa2_b[3] = {(const float*)d_in[21], (const float*)d_in[23], (const float*)d_in[25]};

  char* ws = (char*)d_ws;
  size_t off = 0;
  auto alloc = [&](size_t bytes) { char* p = ws + off; off += (bytes + 255) & ~(size_t)255; return p; };
  // big slots: y0 lives in low half of bigA; y2 overlays whole bigA (y0 dead by mm2); y1 in bigB
  float* bigA = (float*)alloc((size_t)NB * 128 * N1 * KNN * 4);  // 67.1MB
  float* bigB = (float*)alloc((size_t)NB * 64 * N1 * KNN * 4);   // 33.6MB
  // smalls (point-major feature tensors)
  float* f1n      = (float*)alloc((size_t)NB * CFEAT * N3C * 4);
  float* f2n      = (float*)alloc((size_t)NB * CFEAT * N3C * 4);
  float* flow0    = (float*)alloc((size_t)NB * N3C * 3 * 4);     // [B][256][3]
  float* flow0_us = (float*)alloc((size_t)NB * N2 * 3 * 4);      // [B][512][3]
  int*   fps1     = (int*)alloc((size_t)NB * N2 * 4);
  int*   knn1     = (int*)alloc((size_t)NB * N2 * KNN * 4);
  float* cf2      = (float*)alloc((size_t)NB * N2 * 64 * 4);     // [B][512][64]
  float* cf1a     = (float*)alloc((size_t)NB * N1 * 64 * 4);     // [B][1024][64]
  int*   fps2     = (int*)alloc((size_t)NB * N1 * 4);
  int*   knn2     = (int*)alloc((size_t)NB * N1 * KNN * 4);
  float* cf1b     = (float*)alloc((size_t)NB * N1 * 128 * 4);    // [B][1024][128]
  float* meanb    = (float*)alloc((size_t)NB * 128 * 4);
  float* rstdb    = (float*)alloc((size_t)NB * 128 * 4);
  (void)ws_size; (void)in_sizes; (void)n_in; (void)out_size;

  // ---- FPS + kNN (independent of everything; fps dominates) ----
  fps_both_kernel<<<2 * NB, 64, 0, stream>>>(pc1_l2, pc1_l1, fps1, fps2);
  knn_both_kernel<<<(NB * N2 + NB * N1) / 4, 256, 0, stream>>>(pc1_l2, fps1, knn1,
                                                               pc1_l1, fps2, knn2);

  // ---- stage A: correlation flow at l3 ----
  norm_feats2_kernel<<<2 * NB * N3C, 256, 0, stream>>>(feats1, feats2, f1n, f2n);
  corr_flow_kernel<<<NB * N3C, 256, 0, stream>>>(f1n, f2n, pc1_l3, pc2_l3, epsilon, flow0);

  // ---- stage B: upsample flow 256 -> 512 (point-major out) ----
  fprop_kernel<3, true><<<NB * (N2 / 256), 256, 0, stream>>>(pc1_l2, pc1_l3, flow0, flow0_us, N2, N3C);

  // ---- stage C: set abstraction 1 (S=512): 6->32->32->64 ----
  {
    const int S = N2, SK = S * KNN;
    float* y0 = bigA;   // [8][32][8192]
    float* y1 = bigB;   // [8][32][8192]
    float* y2 = bigA;   // [8][64][8192] overlays y0 (dead)
    mm0_kernel<3, 32><<<NB * SK / 256, 256, 0, stream>>>(pc1_l2, flow0_us, fps1, knn1, sa1_w[0], y0, S);
    stats_kernel<<<NB * 32, 256, 0, stream>>>(y0, meanb, rstdb, SK);
    mm_norm_kernel<32, 32><<<NB * (SK / 256), 256, 0, stream>>>(y0, sa1_w[1], meanb, rstdb,
                                                                sa1_g[0], sa1_b[0], y1, SK);
    stats_kernel<<<NB * 32, 256, 0, stream>>>(y1, meanb, rstdb, SK);
    mm_norm_kernel<32, 64><<<NB * (SK / 256), 256, 0, stream>>>(y1, sa1_w[2], meanb, rstdb,
                                                                sa1_g[1], sa1_b[1], y2, SK);
    stats_kernel<<<NB * 64, 256, 0, stream>>>(y2, meanb, rstdb, SK);
    maxpool_norm_kernel<64><<<NB * 64 * S / 256, 256, 0, stream>>>(y2, meanb, rstdb,
                                                                   sa1_g[2], sa1_b[2], cf2, S);
  }

  // ---- stage D: propagate cf2 512 -> 1024 (point-major out) ----
  fprop_kernel<64, true><<<NB * (N1 / 256), 256, 0, stream>>>(pc1_l1, pc1_l2, cf2, cf1a, N1, N2);

  // ---- stage E: set abstraction 2 (S=1024): 67->64->64->128 ----
  {
    const int S = N1, SK = S * KNN;
    float* y0 = bigA;   // [8][64][16384]
    float* y1 = bigB;   // [8][64][16384]
    float* y2 = bigA;   // [8][128][16384] overlays y0 (dead)
    mm0_kernel<64, 64><<<NB * SK / 256, 256, 0, stream>>>(pc1_l1, cf1a, fps2, knn2, sa2_w[0], y0, S);
    stats_kernel<<<NB * 64, 256, 0, stream>>>(y0, meanb, rstdb, SK);
    mm_norm_kernel<64, 64><<<NB * (SK / 256), 256, 0, stream>>>(y0, sa2_w[1], meanb, rstdb,
                                                                sa2_g[0], sa2_b[0], y1, SK);
    stats_kernel<<<NB * 64, 256, 0, stream>>>(y1, meanb, rstdb, SK);
    mm_norm_kernel<64, 128><<<NB * (SK / 256), 256, 0, stream>>>(y1, sa2_w[2], meanb, rstdb,
                                                                 sa2_g[1], sa2_b[1], y2, SK);
    stats_kernel<<<NB * 128, 256, 0, stream>>>(y2, meanb, rstdb, SK);
    maxpool_norm_kernel<128><<<NB * 128 * S / 256, 256, 0, stream>>>(y2, meanb, rstdb,
                                                                     sa2_g[2], sa2_b[2], cf1b, S);
  }

  // ---- stage F: final propagate 1024 -> 8192 into d_out (channel-major) ----
  fprop_kernel<128, false><<<NB * (N0 / 256), 256, 0, stream>>>(pc1_l0, pc1_l1, cf1b,
                                                                (float*)d_out, N0, N1);
}

// Round 4
// 1120.986 us; speedup vs baseline: 1.9839x; 1.1036x over previous
//
#include <hip/hip_runtime.h>
#include <math.h>

#define NB 8
#define N0 8192
#define N1 1024
#define N2 512
#define N3C 256
#define CFEAT 256
#define KNN 16

typedef float v2f __attribute__((ext_vector_type(2)));

// VOP3P packed f32 (CDNA2+), per-component IEEE rn — same rounding as scalar.
static __device__ __forceinline__ v2f pk_add(v2f a, v2f b) {
  v2f r; asm("v_pk_add_f32 %0, %1, %2" : "=v"(r) : "v"(a), "v"(b)); return r;
}
static __device__ __forceinline__ v2f pk_mul(v2f a, v2f b) {
  v2f r; asm("v_pk_mul_f32 %0, %1, %2" : "=v"(r) : "v"(a), "v"(b)); return r;
}

// ---------- f64-key DPP wave64 max: key = {hi=dist_bits(>=0), lo=~idx} ----------
// positive doubles => numeric order == 64-bit pattern order => lexicographic (dist, ~idx)
template <int CTRL, int RM>
static __device__ __forceinline__ double dpp_fmax64(double m) {
  int mh = __double2hiint(m), ml = __double2loint(m);
  int ch = __builtin_amdgcn_update_dpp(mh, mh, CTRL, RM, 0xF, false);
  int cl = __builtin_amdgcn_update_dpp(ml, ml, CTRL, RM, 0xF, false);
  return fmax(m, __hiloint2double(ch, cl));
}
static __device__ __forceinline__ double wave_fmax64(double m) {
  m = dpp_fmax64<0x111, 0xF>(m);  // row_shr:1
  m = dpp_fmax64<0x112, 0xF>(m);  // row_shr:2
  m = dpp_fmax64<0x114, 0xF>(m);  // row_shr:4
  m = dpp_fmax64<0x118, 0xF>(m);  // row_shr:8
  m = dpp_fmax64<0x142, 0xA>(m);  // row_bcast:15
  m = dpp_fmax64<0x143, 0xC>(m);  // row_bcast:31 -> lane 63 complete
  return m;
}

// ---------- DPP wave64 (key,idx) pair reduction for kNN (min) — proven in R2/R3 ----------
template <int CTRL, int RM, bool MAXSEL>
static __device__ __forceinline__ void dpp_step(uint32_t& hi, uint32_t& lo) {
  uint32_t chi = (uint32_t)__builtin_amdgcn_update_dpp((int)hi, (int)hi, CTRL, RM, 0xF, false);
  uint32_t clo = (uint32_t)__builtin_amdgcn_update_dpp((int)lo, (int)lo, CTRL, RM, 0xF, false);
  unsigned long long cand = ((unsigned long long)chi << 32) | clo;
  unsigned long long cur  = ((unsigned long long)hi  << 32) | lo;
  bool take = MAXSEL ? (cand > cur) : (cand < cur);
  if (take) { hi = chi; lo = clo; }
}
template <bool MAXSEL>
static __device__ __forceinline__ void wave_reduce_pair(uint32_t& hi, uint32_t& lo) {
  dpp_step<0x111, 0xF, MAXSEL>(hi, lo);
  dpp_step<0x112, 0xF, MAXSEL>(hi, lo);
  dpp_step<0x114, 0xF, MAXSEL>(hi, lo);
  dpp_step<0x118, 0xF, MAXSEL>(hi, lo);
  dpp_step<0x142, 0xA, MAXSEL>(hi, lo);
  dpp_step<0x143, 0xC, MAXSEL>(hi, lo);
}

// ---------------- 1. per-point inverse L2 norms only: rn[b][n] = 1/sqrt(sum f^2 + 1e-8) ----------------
__global__ void rnorm_kernel(const float* __restrict__ fa, const float* __restrict__ fb,
                             float* __restrict__ ra, float* __restrict__ rb) {
  int blk = blockIdx.x;
  const float* f; float* r;
  if (blk >= NB) { f = fb + (size_t)(blk - NB) * CFEAT * N3C; r = rb + (size_t)(blk - NB) * N3C; }
  else           { f = fa + (size_t)blk * CFEAT * N3C;        r = ra + (size_t)blk * N3C; }
  int m = threadIdx.x;              // 256 threads == N3C points
  float s = 0.f;
  for (int c = 0; c < CFEAT; c++) { float v = f[(size_t)c * N3C + m]; s += v * v; }
  r[m] = 1.0f / sqrtf(s + 1e-8f);
}

// ---------------- 2. correlation + flow0 (raw feats x rn1 x rn2), out [B][N3][3] ----------------
__global__ void corr_flow_kernel(const float* __restrict__ f1, const float* __restrict__ f2,
                                 const float* __restrict__ rn1, const float* __restrict__ rn2,
                                 const float* __restrict__ p1, const float* __restrict__ p2,
                                 const float* __restrict__ eps_in, float* __restrict__ flow0) {
  int bn = blockIdx.x;
  int b = bn / N3C, n = bn % N3C;
  int m = threadIdx.x;               // 256 threads == N3C
  __shared__ float f1c[CFEAT];
  __shared__ float p1s[3];
  f1c[m] = f1[((size_t)b * CFEAT + m) * N3C + n];
  if (m < 3) p1s[m] = p1[((size_t)b * 3 + m) * N3C + n];
  __syncthreads();
  float eps = expf(eps_in[0]) + 0.03f;
  const float* f2b = f2 + (size_t)b * CFEAT * N3C;
  float dot = 0.f;
  for (int c = 0; c < CFEAT; c++) dot += f1c[c] * f2b[(size_t)c * N3C + m];
  float Cv = 1.0f - dot * rn1[b * N3C + n] * rn2[b * N3C + m];
  float p2x = p2[((size_t)b * 3 + 0) * N3C + m];
  float p2y = p2[((size_t)b * 3 + 1) * N3C + m];
  float p2z = p2[((size_t)b * 3 + 2) * N3C + m];
  float n1v = p1s[0] * p1s[0] + p1s[1] * p1s[1] + p1s[2] * p1s[2];
  float n2v = p2x * p2x + p2y * p2y + p2z * p2z;
  float dd = n1v + n2v - 2.0f * (p1s[0] * p2x + p1s[1] * p2y + p1s[2] * p2z);
  float corr = (dd < 100.0f) ? expf(-Cv / eps) : 0.0f;
  float s0 = corr, s1 = corr * p2x, s2 = corr * p2y, s3 = corr * p2z;
  for (int off = 32; off; off >>= 1) {
    s0 += __shfl_xor(s0, off, 64); s1 += __shfl_xor(s1, off, 64);
    s2 += __shfl_xor(s2, off, 64); s3 += __shfl_xor(s3, off, 64);
  }
  __shared__ float red[4][4];
  int wid = threadIdx.x >> 6;
  if ((threadIdx.x & 63) == 0) { red[wid][0] = s0; red[wid][1] = s1; red[wid][2] = s2; red[wid][3] = s3; }
  __syncthreads();
  if (threadIdx.x == 0) {
    float r0 = red[0][0] + red[1][0] + red[2][0] + red[3][0];
    float r1 = red[0][1] + red[1][1] + red[2][1] + red[3][1];
    float r2 = red[0][2] + red[1][2] + red[2][2] + red[3][2];
    float r3 = red[0][3] + red[1][3] + red[2][3] + red[3][3];
    float inv = 1.0f / (r0 + 1e-8f);
    float* fo = flow0 + ((size_t)b * N3C + n) * 3;
    fo[0] = r1 * inv - p1s[0];
    fo[1] = r2 * inv - p1s[1];
    fo[2] = r3 * inv - p1s[2];
  }
}

// ---------------- 3. 3-NN inverse-distance interpolation (featT is [B][S][C]) ----------------
template <int C, bool TOUT>
__global__ void fprop_kernel(const float* __restrict__ xyz1, const float* __restrict__ xyz2,
                             const float* __restrict__ featT, float* __restrict__ out,
                             int N, int S) {
  __shared__ float sm[4 * 1024];   // x2[3][S] + n2[S], S<=1024
  float* x2s = sm;
  float* n2s = sm + 3 * S;
  int tilesPerB = N / 256;
  int b = blockIdx.x / tilesPerB;
  int n = (blockIdx.x % tilesPerB) * 256 + threadIdx.x;
  for (int i = threadIdx.x; i < S; i += 256) {
    float xx = xyz2[((size_t)b * 3 + 0) * S + i];
    float yy = xyz2[((size_t)b * 3 + 1) * S + i];
    float zz = xyz2[((size_t)b * 3 + 2) * S + i];
    x2s[i] = xx; x2s[S + i] = yy; x2s[2 * S + i] = zz;
    n2s[i] = xx * xx + yy * yy + zz * zz;
  }
  __syncthreads();
  float X = xyz1[((size_t)b * 3 + 0) * N + n];
  float Y = xyz1[((size_t)b * 3 + 1) * N + n];
  float Z = xyz1[((size_t)b * 3 + 2) * N + n];
  float n1v = X * X + Y * Y + Z * Z;
  float d0 = 1e30f, d1 = 1e30f, d2 = 1e30f;
  int i0 = 0, i1 = 0, i2 = 0;
  for (int s = 0; s < S; s++) {
    float d = n1v + n2s[s] - 2.0f * (X * x2s[s] + Y * x2s[S + s] + Z * x2s[2 * S + s]);
    if (d < d0)      { d2 = d1; i2 = i1; d1 = d0; i1 = i0; d0 = d; i0 = s; }
    else if (d < d1) { d2 = d1; i2 = i1; d1 = d; i1 = s; }
    else if (d < d2) { d2 = d; i2 = s; }
  }
  float w0 = 1.0f / (d0 + 1e-8f), w1 = 1.0f / (d1 + 1e-8f), w2 = 1.0f / (d2 + 1e-8f);
  float wsum = w0 + w1 + w2;
  w0 /= wsum; w1 /= wsum; w2 /= wsum;
  const float* g0 = featT + ((size_t)b * S + i0) * C;
  const float* g1 = featT + ((size_t)b * S + i1) * C;
  const float* g2 = featT + ((size_t)b * S + i2) * C;
  if constexpr (C % 4 == 0) {
    const float4* v0 = (const float4*)g0;
    const float4* v1 = (const float4*)g1;
    const float4* v2 = (const float4*)g2;
#pragma unroll 4
    for (int c4 = 0; c4 < C / 4; c4++) {
      float4 a = v0[c4], bb = v1[c4], cc = v2[c4];
      float4 r;
      r.x = w0 * a.x + w1 * bb.x + w2 * cc.x;
      r.y = w0 * a.y + w1 * bb.y + w2 * cc.y;
      r.z = w0 * a.z + w1 * bb.z + w2 * cc.z;
      r.w = w0 * a.w + w1 * bb.w + w2 * cc.w;
      if constexpr (TOUT) {
        ((float4*)(out + ((size_t)b * N + n) * C))[c4] = r;
      } else {
        out[((size_t)b * C + 4 * c4 + 0) * N + n] = r.x;
        out[((size_t)b * C + 4 * c4 + 1) * N + n] = r.y;
        out[((size_t)b * C + 4 * c4 + 2) * N + n] = r.z;
        out[((size_t)b * C + 4 * c4 + 3) * N + n] = r.w;
      }
    }
  } else {
#pragma unroll
    for (int c = 0; c < C; c++) {
      float val = w0 * g0[c] + w1 * g1[c] + w2 * g2[c];
      if constexpr (TOUT) out[((size_t)b * N + n) * C + c] = val;
      else                out[((size_t)b * C + c) * N + n] = val;
    }
  }
}

// ---------------- 4. FPS: f64-key tree + f64-key DPP reduce (short dep chain) ----------------
template <int N, int PPL>   // N == 64*PPL
static __device__ __forceinline__ void fps_impl(const float* __restrict__ xyz,
                                                int* __restrict__ idx_out, int b, float4* sm) {
  int lane = threadIdx.x;   // 64 threads
  for (int i = lane; i < N; i += 64) {
    float4 v;
    v.x = xyz[((size_t)b * 3 + 0) * N + i];
    v.y = xyz[((size_t)b * 3 + 1) * N + i];
    v.z = xyz[((size_t)b * 3 + 2) * N + i];
    v.w = 0.f;
    sm[i] = v;
  }
  __syncthreads();
  v2f px[PPL / 2], py[PPL / 2], pz[PPL / 2];
  double key[PPL];          // {hi = dist float bits (>=0), lo = ~global_idx}
  int nlo[PPL];
#pragma unroll
  for (int k = 0; k < PPL / 2; k++) {
    float4 a = sm[lane * PPL + 2 * k];
    float4 c = sm[lane * PPL + 2 * k + 1];
    px[k] = v2f{a.x, c.x}; py[k] = v2f{a.y, c.y}; pz[k] = v2f{a.z, c.z};
    nlo[2 * k]     = ~(lane * PPL + 2 * k);
    nlo[2 * k + 1] = ~(lane * PPL + 2 * k + 1);
    key[2 * k]     = __hiloint2double(__float_as_int(1e10f), nlo[2 * k]);
    key[2 * k + 1] = __hiloint2double(__float_as_int(1e10f), nlo[2 * k + 1]);
  }
  int far = 0;
  idx_out += (size_t)b * N;
  for (int t = 0; t < N; t++) {
    if (lane == 0) idx_out[t] = far;   // scan emits carry BEFORE update
    float4 f = sm[far];
    v2f nfx = v2f{-f.x, -f.x}, nfy = v2f{-f.y, -f.y}, nfz = v2f{-f.z, -f.z};
    // dist update: x+(-y) == x-y exactly; pk ops rn per component.
    // key-min == fminf on dist (lo halves are per-slot constants).
#pragma unroll
    for (int k = 0; k < PPL / 2; k++) {
      v2f dx = pk_add(px[k], nfx);
      v2f dy = pk_add(py[k], nfy);
      v2f dz = pk_add(pz[k], nfz);
      v2f dd = pk_add(pk_add(pk_mul(dx, dx), pk_mul(dy, dy)), pk_mul(dz, dz));
      key[2 * k]     = fmin(key[2 * k],     __hiloint2double(__float_as_int(dd.x), nlo[2 * k]));
      key[2 * k + 1] = fmin(key[2 * k + 1], __hiloint2double(__float_as_int(dd.y), nlo[2 * k + 1]));
    }
    // per-lane tree max (depth log2(PPL)) — ties resolve to lowest idx via ~idx in lo
    double tv[PPL / 2];
#pragma unroll
    for (int i = 0; i < PPL / 2; i++) tv[i] = fmax(key[2 * i], key[2 * i + 1]);
#pragma unroll
    for (int s = PPL / 4; s >= 1; s >>= 1)
#pragma unroll
      for (int i = 0; i < s; i++) tv[i] = fmax(tv[i], tv[i + s]);
    // cross-lane f64 DPP max; winner's ~idx rides along in lo
    double M = wave_fmax64(tv[0]);
    far = ~__builtin_amdgcn_readlane(__double2loint(M), 63);
  }
}

__global__ void fps_both_kernel(const float* __restrict__ xyz_l2, const float* __restrict__ xyz_l1,
                                int* __restrict__ fps1, int* __restrict__ fps2) {
  __shared__ float4 sm[1024];
  if (blockIdx.x < NB) fps_impl<N2, N2 / 64>(xyz_l2, fps1, blockIdx.x, sm);
  else                 fps_impl<N1, N1 / 64>(xyz_l1, fps2, blockIdx.x - NB, sm);
}

// ---------------- 5. 16-NN per FPS center (DPP extract-min x16, proven) ----------------
template <int S, int PPL>
static __device__ __forceinline__ void knn_impl(const float* __restrict__ xyz,
                                                const int* __restrict__ fps_idx,
                                                int* __restrict__ knn_out, int gw) {
  int lane = threadIdx.x & 63;
  int b = gw / S, s = gw % S;
  int center = fps_idx[(size_t)b * S + s];
  const float* xb = xyz + (size_t)b * 3 * S;
  float cx = xb[center], cy = xb[S + center], cz = xb[2 * S + center];
  float cn = cx * cx + cy * cy + cz * cz;
  uint32_t kb[PPL];
#pragma unroll
  for (int j = 0; j < PPL; j++) {
    int g = lane * PPL + j;
    float x = xb[g], y = xb[S + g], z = xb[2 * S + g];
    float pn = x * x + y * y + z * z;
    float d = cn + pn - 2.0f * (cx * x + cy * y + cz * z);
    uint32_t bts = __float_as_uint(d);
    kb[j] = bts ^ ((uint32_t)((int)bts >> 31) | 0x80000000u);  // order-monotonic for all floats
  }
  int* ob = knn_out + ((size_t)b * S + s) * KNN;
  for (int r = 0; r < KNN; r++) {
    uint32_t bh = 0xFFFFFFFFu, bl = 0xFFFFFFFFu;
#pragma unroll
    for (int j = 0; j < PPL; j++) {
      unsigned long long cand = ((unsigned long long)kb[j] << 32) | (uint32_t)(lane * PPL + j);
      unsigned long long cur  = ((unsigned long long)bh << 32) | bl;
      if (cand < cur) { bh = kb[j]; bl = (uint32_t)(lane * PPL + j); }
    }
    wave_reduce_pair<false>(bh, bl);
    uint32_t widx = (uint32_t)__builtin_amdgcn_readlane((int)bl, 63);
    if (lane == 0) ob[r] = (int)widx;
#pragma unroll
    for (int j = 0; j < PPL; j++)
      if ((uint32_t)(lane * PPL + j) == widx) kb[j] = 0xFFFFFFFFu;
  }
}

__global__ void knn_both_kernel(const float* __restrict__ xyz_l2, const int* __restrict__ fps1,
                                int* __restrict__ knn1,
                                const float* __restrict__ xyz_l1, const int* __restrict__ fps2,
                                int* __restrict__ knn2) {
  int gw = blockIdx.x * 4 + (threadIdx.x >> 6);
  if (gw < NB * N2) knn_impl<N2, N2 / 64>(xyz_l2, fps1, knn1, gw);
  else              knn_impl<N1, N1 / 64>(xyz_l1, fps2, knn2, gw - NB * N2);
}

// ---------------- 6. layer-0 matmul with fused gather (group+mm) ----------------
template <int CF, int D>
__global__ void mm0_kernel(const float* __restrict__ xyz, const float* __restrict__ featsT,
                           const int* __restrict__ fps_idx, const int* __restrict__ knn,
                           const float* __restrict__ w, float* __restrict__ y, int S) {
  const int SK = S * KNN;
  int t = blockIdx.x * 256 + threadIdx.x;
  if (t >= NB * SK) return;
  int b = t / SK, sk = t % SK, s = sk / KNN;
  int nb = knn[(size_t)b * SK + sk];
  int ctr = fps_idx[(size_t)b * S + s];
  const float* xb = xyz + (size_t)b * 3 * S;
  float r0 = xb[nb] - xb[ctr];
  float r1 = xb[S + nb] - xb[S + ctr];
  float r2 = xb[2 * S + nb] - xb[2 * S + ctr];
  float acc[D];
#pragma unroll
  for (int i = 0; i < D; i++)
    acc[i] = fmaf(r0, w[i], fmaf(r1, w[D + i], r2 * w[2 * D + i]));
  const float* pb = featsT + ((size_t)b * S + nb) * CF;
  if constexpr (CF % 4 == 0) {
    const float4* pv = (const float4*)pb;
    for (int c4 = 0; c4 < CF / 4; c4++) {
      float4 v = pv[c4];
      const float* wr = w + (size_t)(3 + 4 * c4) * D;
#pragma unroll
      for (int i = 0; i < D; i++)
        acc[i] = fmaf(v.x, wr[i],
                 fmaf(v.y, wr[D + i],
                 fmaf(v.z, wr[2 * D + i],
                 fmaf(v.w, wr[3 * D + i], acc[i]))));
    }
  } else {
#pragma unroll
    for (int c = 0; c < CF; c++) {
      float xv = pb[c];
      const float* wr = w + (size_t)(3 + c) * D;
#pragma unroll
      for (int i = 0; i < D; i++) acc[i] = fmaf(xv, wr[i], acc[i]);
    }
  }
  float* yb = y + (size_t)b * D * SK + sk;
#pragma unroll
  for (int i = 0; i < D; i++) yb[(size_t)i * SK] = acc[i];
}

// ---------------- 7. matmul with fused input-normalize+relu ----------------
template <int Cin, int D>
__global__ void mm_norm_kernel(const float* __restrict__ x, const float* __restrict__ w,
                               const float* __restrict__ mean, const float* __restrict__ rstd,
                               const float* __restrict__ g, const float* __restrict__ beta,
                               float* __restrict__ y, int SK) {
  int tilesPerB = SK / 256;
  int b = blockIdx.x / tilesPerB;
  int sk = (blockIdx.x % tilesPerB) * 256 + threadIdx.x;
  const float* xb = x + (size_t)b * Cin * SK + sk;
  float* yb = y + (size_t)b * D * SK + sk;
  float acc[D];
#pragma unroll
  for (int i = 0; i < D; i++) acc[i] = 0.f;
  for (int c = 0; c < Cin; c++) {
    float mu = mean[b * Cin + c], rs = rstd[b * Cin + c];
    float sc = rs * g[c];
    float sh = fmaf(-mu, sc, beta[c]);
    float xv = fmaxf(fmaf(xb[(size_t)c * SK], sc, sh), 0.f);
    const float* wr = w + (size_t)c * D;
#pragma unroll
    for (int i = 0; i < D; i++) acc[i] = fmaf(xv, wr[i], acc[i]);
  }
#pragma unroll
  for (int i = 0; i < D; i++) yb[(size_t)i * SK] = acc[i];
}

// ---------------- 8. instance-norm stats per (b,d) ----------------
__global__ void stats_kernel(const float* __restrict__ y, float* __restrict__ mean,
                             float* __restrict__ rstd, int SK) {
  int bd = blockIdx.x;
  const float* p = y + (size_t)bd * SK;
  float s = 0.f, sq = 0.f;
  for (int i = threadIdx.x; i < SK; i += 256) { float v = p[i]; s += v; sq += v * v; }
  for (int off = 32; off; off >>= 1) { s += __shfl_xor(s, off, 64); sq += __shfl_xor(sq, off, 64); }
  __shared__ float sa[4], sb[4];
  int wid = threadIdx.x >> 6;
  if ((threadIdx.x & 63) == 0) { sa[wid] = s; sb[wid] = sq; }
  __syncthreads();
  if (threadIdx.x == 0) {
    float S1 = sa[0] + sa[1] + sa[2] + sa[3];
    float S2 = sb[0] + sb[1] + sb[2] + sb[3];
    float mu = S1 / (float)SK;
    float var = S2 / (float)SK - mu * mu;
    mean[bd] = mu;
    rstd[bd] = 1.0f / sqrtf(var + 1e-5f);
  }
}

// ---------------- 9. fused normalize+relu+max-over-K; writes point-major [B][S][D] ----------------
template <int D>
__global__ void maxpool_norm_kernel(const float* __restrict__ y, const float* __restrict__ mean,
                                    const float* __restrict__ rstd, const float* __restrict__ g,
                                    const float* __restrict__ beta, float* __restrict__ outT, int S) {
  int t = blockIdx.x * 256 + threadIdx.x;      // t = (b*D + d)*S + s
  if (t >= NB * D * S) return;
  int s = t % S;
  int bd = t / S;
  int d = bd % D, b = bd / D;
  float mu = mean[bd], sc = rstd[bd] * g[d];
  float sh = fmaf(-mu, sc, beta[d]);
  const float4* p = (const float4*)(y + (size_t)t * KNN);
  float m = -1e30f;
#pragma unroll
  for (int q = 0; q < 4; q++) {
    float4 v = p[q];
    m = fmaxf(m, fmaf(v.x, sc, sh)); m = fmaxf(m, fmaf(v.y, sc, sh));
    m = fmaxf(m, fmaf(v.z, sc, sh)); m = fmaxf(m, fmaf(v.w, sc, sh));
  }
  outT[((size_t)b * S + s) * D + d] = fmaxf(m, 0.f);   // relu(max) == max(relu)
}

extern "C" void kernel_launch(void* const* d_in, const int* in_sizes, int n_in,
                              void* d_out, int out_size, void* d_ws, size_t ws_size,
                              hipStream_t stream) {
  const float* pc1_l0 = (const float*)d_in[0];
  const float* pc1_l1 = (const float*)d_in[1];
  const float* pc1_l2 = (const float*)d_in[2];
  const float* pc1_l3 = (const float*)d_in[3];
  const float* pc2_l3 = (const float*)d_in[4];
  const float* feats1 = (const float*)d_in[5];
  const float* feats2 = (const float*)d_in[6];
  const float* epsilon = (const float*)d_in[7];
  const float* sa1_w[3] = {(const float*)d_in[8], (const float*)d_in[9], (const float*)d_in[10]};
  const float* sa1_g[3] = {(const float*)d_in[11], (const float*)d_in[13], (const float*)d_in[15]};
  const float* sa1_b[3] = {(const float*)d_in[12], (const float*)d_in[14], (const float*)d_in[16]};
  const float* sa2_w[3] = {(const float*)d_in[17], (const float*)d_in[18], (const float*)d_in[19]};
  const float* sa2_g[3] = {(const float*)d_in[20], (const float*)d_in[22], (const float*)d_in[24]};
  const float* sa2_b[3] = {(const float*)d_in[21], (const float*)d_in[23], (const float*)d_in[25]};

  char* ws = (char*)d_ws;
  size_t off = 0;
  auto alloc = [&](size_t bytes) { char* p = ws + off; off += (bytes + 255) & ~(size_t)255; return p; };
  float* bigA = (float*)alloc((size_t)NB * 128 * N1 * KNN * 4);  // 67.1MB
  float* bigB = (float*)alloc((size_t)NB * 64 * N1 * KNN * 4);   // 33.6MB
  float* rn1      = (float*)alloc((size_t)NB * N3C * 4);
  float* rn2      = (float*)alloc((size_t)NB * N3C * 4);
  float* flow0    = (float*)alloc((size_t)NB * N3C * 3 * 4);     // [B][256][3]
  float* flow0_us = (float*)alloc((size_t)NB * N2 * 3 * 4);      // [B][512][3]
  int*   fps1     = (int*)alloc((size_t)NB * N2 * 4);
  int*   knn1     = (int*)alloc((size_t)NB * N2 * KNN * 4);
  float* cf2      = (float*)alloc((size_t)NB * N2 * 64 * 4);     // [B][512][64]
  float* cf1a     = (float*)alloc((size_t)NB * N1 * 64 * 4);     // [B][1024][64]
  int*   fps2     = (int*)alloc((size_t)NB * N1 * 4);
  int*   knn2     = (int*)alloc((size_t)NB * N1 * KNN * 4);
  float* cf1b     = (float*)alloc((size_t)NB * N1 * 128 * 4);    // [B][1024][128]
  float* meanb    = (float*)alloc((size_t)NB * 128 * 4);
  float* rstdb    = (float*)alloc((size_t)NB * 128 * 4);
  (void)ws_size; (void)in_sizes; (void)n_in; (void)out_size;

  // ---- FPS + kNN ----
  fps_both_kernel<<<2 * NB, 64, 0, stream>>>(pc1_l2, pc1_l1, fps1, fps2);
  knn_both_kernel<<<(NB * N2 + NB * N1) / 4, 256, 0, stream>>>(pc1_l2, fps1, knn1,
                                                               pc1_l1, fps2, knn2);

  // ---- stage A: correlation flow at l3 ----
  rnorm_kernel<<<2 * NB, 256, 0, stream>>>(feats1, feats2, rn1, rn2);
  corr_flow_kernel<<<NB * N3C, 256, 0, stream>>>(feats1, feats2, rn1, rn2,
                                                 pc1_l3, pc2_l3, epsilon, flow0);

  // ---- stage B: upsample flow 256 -> 512 ----
  fprop_kernel<3, true><<<NB * (N2 / 256), 256, 0, stream>>>(pc1_l2, pc1_l3, flow0, flow0_us, N2, N3C);

  // ---- stage C: set abstraction 1 (S=512): 6->32->32->64 ----
  {
    const int S = N2, SK = S * KNN;
    float* y0 = bigA;
    float* y1 = bigB;
    float* y2 = bigA;   // overlays y0 (dead)
    mm0_kernel<3, 32><<<NB * SK / 256, 256, 0, stream>>>(pc1_l2, flow0_us, fps1, knn1, sa1_w[0], y0, S);
    stats_kernel<<<NB * 32, 256, 0, stream>>>(y0, meanb, rstdb, SK);
    mm_norm_kernel<32, 32><<<NB * (SK / 256), 256, 0, stream>>>(y0, sa1_w[1], meanb, rstdb,
                                                                sa1_g[0], sa1_b[0], y1, SK);
    stats_kernel<<<NB * 32, 256, 0, stream>>>(y1, meanb, rstdb, SK);
    mm_norm_kernel<32, 64><<<NB * (SK / 256), 256, 0, stream>>>(y1, sa1_w[2], meanb, rstdb,
                                                                sa1_g[1], sa1_b[1], y2, SK);
    stats_kernel<<<NB * 64, 256, 0, stream>>>(y2, meanb, rstdb, SK);
    maxpool_norm_kernel<64><<<NB * 64 * S / 256, 256, 0, stream>>>(y2, meanb, rstdb,
                                                                   sa1_g[2], sa1_b[2], cf2, S);
  }

  // ---- stage D: propagate cf2 512 -> 1024 ----
  fprop_kernel<64, true><<<NB * (N1 / 256), 256, 0, stream>>>(pc1_l1, pc1_l2, cf2, cf1a, N1, N2);

  // ---- stage E: set abstraction 2 (S=1024): 67->64->64->128 ----
  {
    const int S = N1, SK = S * KNN;
    float* y0 = bigA;
    float* y1 = bigB;
    float* y2 = bigA;   // overlays y0 (dead)
    mm0_kernel<64, 64><<<NB * SK / 256, 256, 0, stream>>>(pc1_l1, cf1a, fps2, knn2, sa2_w[0], y0, S);
    stats_kernel<<<NB * 64, 256, 0, stream>>>(y0, meanb, rstdb, SK);
    mm_norm_kernel<64, 64><<<NB * (SK / 256), 256, 0, stream>>>(y0, sa2_w[1], meanb, rstdb,
                                                                sa2_g[0], sa2_b[0], y1, SK);
    stats_kernel<<<NB * 64, 256, 0, stream>>>(y1, meanb, rstdb, SK);
    mm_norm_kernel<64, 128><<<NB * (SK / 256), 256, 0, stream>>>(y1, sa2_w[2], meanb, rstdb,
                                                                 sa2_g[1], sa2_b[1], y2, SK);
    stats_kernel<<<NB * 128, 256, 0, stream>>>(y2, meanb, rstdb, SK);
    maxpool_norm_kernel<128><<<NB * 128 * S / 256, 256, 0, stream>>>(y2, meanb, rstdb,
                                                                     sa2_g[2], sa2_b[2], cf1b, S);
  }

  // ---- stage F: final propagate 1024 -> 8192 into d_out ----
  fprop_kernel<128, false><<<NB * (N0 / 256), 256, 0, stream>>>(pc1_l0, pc1_l1, cf1b,
                                                                (float*)d_out, N0, N1);
}